// Round 4
// baseline (434.043 us; speedup 1.0000x reference)
//
#include <hip/hip_runtime.h>

typedef unsigned short u16;
typedef __attribute__((ext_vector_type(8))) short short8;
typedef __attribute__((ext_vector_type(4))) float f32x4;

#define GLDS16(gp, sp) __builtin_amdgcn_global_load_lds( \
    (const __attribute__((address_space(1))) void*)(gp),  \
    (__attribute__((address_space(3))) void*)(sp), 16, 0, 0)

__device__ __forceinline__ u16 f2bf(float f) {
  union { float f; unsigned u; } x; x.f = f;
  unsigned r = (x.u + 0x7fffu + ((x.u >> 16) & 1u)) >> 16;  // RNE
  return (u16)r;
}
__device__ __forceinline__ float bf2f(u16 v) {
  union { unsigned u; float f; } x; x.u = ((unsigned)v) << 16; return x.f;
}
__device__ __forceinline__ unsigned cvt_pk_bf16(float lo, float hi) {
  unsigned r;
  asm("v_cvt_pk_bf16_f32 %0, %1, %2" : "=v"(r) : "v"(lo), "v"(hi));
  return r;
}
__device__ __forceinline__ float gelu_t(float v) {
  float i = v * (1.f + 0.044715f * v * v);
  float e = __expf(-1.5957691216057308f * i);
  return v * __builtin_amdgcn_rcpf(1.f + e);
}

// ------- generic weight -> bf16 MFMA B-fragment order --------------------
__global__ __launch_bounds__(256) void wswizB(const float* __restrict__ W,
                                              u16* __restrict__ Wf, int K, int N) {
  int tid = blockIdx.x * 256 + threadIdx.x;
  int Kt = K >> 5, Nt = N >> 4;
  int per = Nt * Kt * 64;
  if (tid >= 2 * per) return;
  int l = tid >= per;
  int rem = tid - l * per;
  int nb = rem / (Kt * 64);
  int rem2 = rem - nb * Kt * 64;
  int ks = rem2 >> 6, lane = rem2 & 63;
  int n = nb * 16 + (lane & 15);
  u16 o[8];
  #pragma unroll
  for (int e = 0; e < 8; ++e) {
    int k = ks * 32 + ((lane >> 4) << 3) + e;
    o[e] = f2bf(W[((size_t)l * K + k) * N + n]);
  }
  *(uint4*)(Wf + ((size_t)tid << 3)) = *(uint4*)o;
}

// ------- fc1 weights -> B-fragment order: W1f[l][hc(8)][ks(8)][ntile(8)][lane][8]
__global__ __launch_bounds__(256) void wswiz1(const float* __restrict__ W,
                                              u16* __restrict__ Wf) {
  int tid = blockIdx.x * 256 + threadIdx.x;  // [0, 65536)
  int lane = tid & 63, nt = (tid >> 6) & 7, ks = (tid >> 9) & 7,
      hc = (tid >> 12) & 7, l = tid >> 15;
  int n = hc * 128 + nt * 16 + (lane & 15);
  u16 o[8];
  #pragma unroll
  for (int e = 0; e < 8; ++e) {
    int k = ks * 32 + ((lane >> 4) << 3) + e;
    o[e] = f2bf(W[((size_t)l * 256 + k) * 1024 + n]);
  }
  *(uint4*)(Wf + ((size_t)tid << 3)) = *(uint4*)o;
}

// ------- fc2 weights -> B-fragment order: W2f[l][hc(8)][ks(4)][ntile(16)][lane][8]
__global__ __launch_bounds__(256) void wswiz2(const float* __restrict__ W,
                                              u16* __restrict__ Wf) {
  int tid = blockIdx.x * 256 + threadIdx.x;  // [0, 65536)
  int lane = tid & 63, nt = (tid >> 6) & 15, ks = (tid >> 10) & 3,
      hc = (tid >> 12) & 7, l = tid >> 15;
  int n = nt * 16 + (lane & 15);
  u16 o[8];
  #pragma unroll
  for (int e = 0; e < 8; ++e) {
    int k = hc * 128 + ks * 32 + ((lane >> 4) << 3) + e;
    o[e] = f2bf(W[((size_t)l * 1024 + k) * 256 + n]);
  }
  *(uint4*)(Wf + ((size_t)tid << 3)) = *(uint4*)o;
}

// ------- rel-pos bias gather, bf16, pre-swizzled to MFMA C-layout ------------
__global__ __launch_bounds__(256) void bias_gb(const float* __restrict__ rpb,
                                               const int* __restrict__ rpi,
                                               u16* __restrict__ biasb) {
  int tid = blockIdx.x * 256 + threadIdx.x;  // [0, 2*65536)
  if (tid >= 131072) return;
  int l = tid >> 16, cid = tid & 65535;
  int lane = cid & 63, k = (cid >> 6) & 7, mslot = (cid >> 9) & 15, h = cid >> 13;
  u16 o[8];
  #pragma unroll
  for (int e = 0; e < 8; ++e) {
    int nt = 2 * k + (e >> 2), r = e & 3;
    int i = mslot * 16 + ((lane >> 4) << 2) + r;
    int j = nt * 16 + (lane & 15);
    int idx = rpi[i * 256 + j];
    o[e] = f2bf(rpb[((size_t)l * 961 + idx) * 8 + h]);
  }
  *(uint4*)(biasb + ((size_t)tid << 3)) = *(uint4*)o;
}

// ---------------- LN1 + shift + window partition -> bf16 wins ---------------
// (v6 form: one row per 64-lane wave, 6-level tree — reverted from v7)
__global__ __launch_bounds__(256) void ln_part(const float* __restrict__ x,
                                               const float* __restrict__ g,
                                               const float* __restrict__ b,
                                               u16* __restrict__ out, int shift) {
  int wv = threadIdx.x >> 6, lane = threadIdx.x & 63;
  int wtok = blockIdx.x * 4 + wv;
  int w = wtok >> 8, t = wtok & 255;
  int bimg = w >> 4, wi = w & 15;
  int ph = (((wi >> 2) << 4) + (t >> 4) + shift) & 63;
  int pw = (((wi & 3) << 4) + (t & 15) + shift) & 63;
  const float4 v = *(const float4*)(x + ((size_t)((bimg * 64 + ph) * 64 + pw)) * 256 + lane * 4);
  float s = v.x + v.y + v.z + v.w;
  float sq = v.x * v.x + v.y * v.y + v.z * v.z + v.w * v.w;
  #pragma unroll
  for (int m = 1; m < 64; m <<= 1) { s += __shfl_xor(s, m, 64); sq += __shfl_xor(sq, m, 64); }
  float mean = s * (1.f / 256.f);
  float var = sq * (1.f / 256.f) - mean * mean;
  float rs = rsqrtf(var + 1e-5f);
  float4 gg = *(const float4*)(g + lane * 4);
  float4 bb = *(const float4*)(b + lane * 4);
  uint2 pk;
  pk.x = cvt_pk_bf16((v.x - mean) * rs * gg.x + bb.x,
                     (v.y - mean) * rs * gg.y + bb.y);
  pk.y = cvt_pk_bf16((v.z - mean) * rs * gg.z + bb.z,
                     (v.w - mean) * rs * gg.w + bb.w);
  *(uint2*)(out + (size_t)wtok * 256 + lane * 4) = pk;
}

struct EpiParams {
  const float* bias;
  u16* obf;
  float* of32;
  const float* resid;
  int shift;
  float qscale;
};

// ---------------- GEMM v2: 128x256 tile, full-K staged, A-read reuse x4 -----
__global__ __launch_bounds__(512, 2) void gemm_fk2(const u16* __restrict__ A,
                                                   const u16* __restrict__ Wf,
                                                   int N, EpiParams ep) {
  __shared__ u16 As[8][128][32];   // 64 KB
  int tid = threadIdx.x;
  int n0 = blockIdx.x * 256, m0 = blockIdx.y * 128;
  int wv = tid >> 6, lane = tid & 63, quad = lane >> 4, l15 = lane & 15;
  int wm = wv & 1, wn = wv >> 1;   // wn in 0..3

  #pragma unroll
  for (int i = 0; i < 8; ++i) {
    int c = i * 512 + tid;
    int kb = c >> 9, rc = c & 511;
    int row = rc >> 2, kc = (rc & 3) * 8;
    GLDS16(A + (size_t)(m0 + row) * 256 + kb * 32 + kc, &As[kb][row][kc]);
  }
  __syncthreads();

  f32x4 acc[4][4] = {};
  #pragma unroll
  for (int kb = 0; kb < 8; ++kb) {
    short8 bf[4];
    #pragma unroll
    for (int nt = 0; nt < 4; ++nt) {
      size_t ntile = (size_t)(blockIdx.x * 16 + wn * 4 + nt);
      bf[nt] = *(const short8*)(Wf + ((ntile * 8 + kb) * 64 + lane) * 8);
    }
    #pragma unroll
    for (int mt = 0; mt < 4; ++mt) {
      short8 af = *(const short8*)&As[kb][wm * 64 + mt * 16 + l15][quad * 8];
      #pragma unroll
      for (int nt = 0; nt < 4; ++nt)
        acc[mt][nt] = __builtin_amdgcn_mfma_f32_16x16x32_bf16(af, bf[nt], acc[mt][nt], 0, 0, 0);
    }
  }

  #pragma unroll
  for (int mt = 0; mt < 4; ++mt) {
    #pragma unroll
    for (int nt = 0; nt < 4; ++nt) {
      #pragma unroll
      for (int r = 0; r < 4; ++r) {
        int grow = m0 + wm * 64 + mt * 16 + quad * 4 + r;
        int gcol = n0 + wn * 64 + nt * 16 + l15;
        float v = acc[mt][nt][r] + ep.bias[gcol];
        if (gcol < 256) v *= ep.qscale;
        ep.obf[(size_t)grow * N + gcol] = f2bf(v);
      }
    }
  }
}

// ---------------- GEMM, full-K staged (round-7, used for proj) --------------
template <int EPI>
__global__ __launch_bounds__(512, 2) void gemm_fk(const u16* __restrict__ A,
                                                  const u16* __restrict__ Wf,
                                                  int N, EpiParams ep) {
  __shared__ u16 As[8][128][32];   // 64 KB
  int tid = threadIdx.x;
  int n0 = blockIdx.x * 128, m0 = blockIdx.y * 128;
  int wv = tid >> 6, lane = tid & 63, quad = lane >> 4, l15 = lane & 15;
  int wm = wv & 1, wn = wv >> 1;

  #pragma unroll
  for (int i = 0; i < 8; ++i) {
    int c = i * 512 + tid;
    int kb = c >> 9, rc = c & 511;
    int row = rc >> 2, kc = (rc & 3) * 8;
    GLDS16(A + (size_t)(m0 + row) * 256 + kb * 32 + kc, &As[kb][row][kc]);
  }
  __syncthreads();

  f32x4 acc[4][2] = {};
  #pragma unroll
  for (int kb = 0; kb < 8; ++kb) {
    short8 bf[2];
    #pragma unroll
    for (int nt = 0; nt < 2; ++nt) {
      size_t ntile = (size_t)(blockIdx.x * 8 + wn * 2 + nt);
      bf[nt] = *(const short8*)(Wf + ((ntile * 8 + kb) * 64 + lane) * 8);
    }
    #pragma unroll
    for (int mt = 0; mt < 4; ++mt) {
      short8 af = *(const short8*)&As[kb][wm * 64 + mt * 16 + l15][quad * 8];
      #pragma unroll
      for (int nt = 0; nt < 2; ++nt)
        acc[mt][nt] = __builtin_amdgcn_mfma_f32_16x16x32_bf16(af, bf[nt], acc[mt][nt], 0, 0, 0);
    }
  }

  #pragma unroll
  for (int mt = 0; mt < 4; ++mt) {
    #pragma unroll
    for (int nt = 0; nt < 2; ++nt) {
      #pragma unroll
      for (int r = 0; r < 4; ++r) {
        int grow = m0 + wm * 64 + mt * 16 + quad * 4 + r;
        int gcol = n0 + wn * 32 + nt * 16 + l15;
        float v = acc[mt][nt][r] + ep.bias[gcol];
        if constexpr (EPI == 0) {
          if (gcol < 256) v *= ep.qscale;
          ep.obf[(size_t)grow * N + gcol] = f2bf(v);
        } else {
          int w_ = grow >> 8, t = grow & 255, wi = w_ & 15;
          int ph = (((wi >> 2) << 4) + (t >> 4) + ep.shift) & 63;
          int pw = (((wi & 3) << 4) + (t & 15) + ep.shift) & 63;
          size_t pix = (size_t)(((w_ >> 4) * 64 + ph) * 64 + pw);
          ep.of32[pix * 256 + gcol] = ep.resid[pix * 256 + gcol] + v;
        }
      }
    }
  }
}

// ---------------- fused MLP v8: 2m x 4n wave split, LDS reads halved --------
// v6 model: LDS pipe ~28us/CU (dominant) vs MFMA 17us. v8: each wave covers
// 32 rows (wm) x quarter-n (wn); each Zs/Hs fragment read now feeds 4 MFMAs
// (was 2) -> ds_read_b128 count per wave halves (256 -> 128). Weight L2
// traffic doubles (both wm halves read the same fragments) — L2-served,
// ~22 TB/s at target duration, acceptable. VGPR ~108 is free: occupancy is
// LDS-capped at 2 blocks/CU regardless.
__global__ __launch_bounds__(512, 4) void fused_mlp(const float* __restrict__ xin,
                                                    const float* __restrict__ g,
                                                    const float* __restrict__ b,
                                                    const u16* __restrict__ W1f,
                                                    const u16* __restrict__ W2f,
                                                    const float* __restrict__ b1p,
                                                    const float* __restrict__ b2p,
                                                    float* __restrict__ out) {
  __shared__ u16 Zs[64 * 264];       // 33792 B
  __shared__ u16 Hs[2][64 * 136];    // 34816 B
  int tid = threadIdx.x, wv = tid >> 6, lane = tid & 63;
  int quad = lane >> 4, l15 = lane & 15;
  int wm = wv & 1, wn = wv >> 1;     // wn in 0..3
  int m0 = blockIdx.x * 64;

  // ---- LN -> Zs (bf16), v6 form ----
  float4 gg = *(const float4*)(g + lane * 4);
  float4 bb = *(const float4*)(b + lane * 4);
  #pragma unroll
  for (int rr = 0; rr < 8; ++rr) {
    int row = wv * 8 + rr;
    const float4 v = *(const float4*)(xin + (size_t)(m0 + row) * 256 + lane * 4);
    float s = v.x + v.y + v.z + v.w;
    float sq = v.x * v.x + v.y * v.y + v.z * v.z + v.w * v.w;
    #pragma unroll
    for (int m = 1; m < 64; m <<= 1) { s += __shfl_xor(s, m, 64); sq += __shfl_xor(sq, m, 64); }
    float mean = s * (1.f / 256.f);
    float var = sq * (1.f / 256.f) - mean * mean;
    float rs = rsqrtf(var + 1e-5f);
    uint2 pk;
    pk.x = cvt_pk_bf16((v.x - mean) * rs * gg.x + bb.x,
                       (v.y - mean) * rs * gg.y + bb.y);
    pk.y = cvt_pk_bf16((v.z - mean) * rs * gg.z + bb.z,
                       (v.w - mean) * rs * gg.w + bb.w);
    *(uint2*)&Zs[row * 264 + lane * 4] = pk;
  }
  __syncthreads();

  // acc2 (transposed): lane holds n = (wn*4+nt)*16 + quad*4 + r,
  //                    m = (wm*2+mt2)*16 + l15
  f32x4 acc2[2][4];
  #pragma unroll
  for (int nt = 0; nt < 4; ++nt) {
    float4 b2 = *(const float4*)(b2p + (wn * 4 + nt) * 16 + quad * 4);
    #pragma unroll
    for (int mt2 = 0; mt2 < 2; ++mt2) {
      acc2[mt2][nt][0] = b2.x; acc2[mt2][nt][1] = b2.y;
      acc2[mt2][nt][2] = b2.z; acc2[mt2][nt][3] = b2.w;
    }
  }

  for (int hp = 0; hp < 4; ++hp) {
    // ---- phase A: pair (hcA=2hp, hcB=2hp+1); wave covers 2 slots per hc ----
    f32x4 acc1[2][4];   // [mt2][j]; j 0..1 -> hcA slots, 2..3 -> hcB slots
    #pragma unroll
    for (int j = 0; j < 4; ++j) {
      int hc = 2 * hp + (j >> 1);
      float4 b1 = *(const float4*)(b1p + hc * 128 + (wn * 2 + (j & 1)) * 16 + quad * 4);
      #pragma unroll
      for (int mt2 = 0; mt2 < 2; ++mt2) {
        acc1[mt2][j][0] = b1.x; acc1[mt2][j][1] = b1.y;
        acc1[mt2][j][2] = b1.z; acc1[mt2][j][3] = b1.w;
      }
    }
    #pragma unroll
    for (int ks = 0; ks < 8; ++ks) {
      short8 w1[4];
      #pragma unroll
      for (int j = 0; j < 4; ++j) {
        int hc = 2 * hp + (j >> 1);
        w1[j] = *(const short8*)(W1f + ((((size_t)hc * 8 + ks) * 8 + wn * 2 + (j & 1)) * 64 + lane) * 8);
      }
      #pragma unroll
      for (int mt2 = 0; mt2 < 2; ++mt2) {
        short8 zf = *(const short8*)&Zs[((wm * 2 + mt2) * 16 + l15) * 264 + ks * 32 + quad * 8];
        #pragma unroll
        for (int j = 0; j < 4; ++j)
          acc1[mt2][j] = __builtin_amdgcn_mfma_f32_16x16x32_bf16(w1[j], zf, acc1[mt2][j], 0, 0, 0);
      }
    }
    // ---- gelu + packed transpose-store (before barrier) ----
    #pragma unroll
    for (int mt2 = 0; mt2 < 2; ++mt2)
      #pragma unroll
      for (int j = 0; j < 4; ++j) {
        uint2 p;
        p.x = cvt_pk_bf16(gelu_t(acc1[mt2][j][0]), gelu_t(acc1[mt2][j][1]));
        p.y = cvt_pk_bf16(gelu_t(acc1[mt2][j][2]), gelu_t(acc1[mt2][j][3]));
        int ha = ((wm * 2 + mt2) * 16 + l15) * 136 + (wn * 2 + (j & 1)) * 16 + quad * 4;
        *(uint2*)&Hs[j >> 1][ha] = p;
      }
    __syncthreads();
    // ---- phase B over both chunks ----
    #pragma unroll
    for (int buf = 0; buf < 2; ++buf) {
      int hc = 2 * hp + buf;
      #pragma unroll
      for (int ks2 = 0; ks2 < 4; ++ks2) {
        short8 w2[4];
        #pragma unroll
        for (int nt = 0; nt < 4; ++nt)
          w2[nt] = *(const short8*)(W2f + ((((size_t)hc * 4 + ks2) * 16 + wn * 4 + nt) * 64 + lane) * 8);
        #pragma unroll
        for (int mt2 = 0; mt2 < 2; ++mt2) {
          short8 hf = *(const short8*)&Hs[buf][((wm * 2 + mt2) * 16 + l15) * 136 + ks2 * 32 + quad * 8];
          #pragma unroll
          for (int nt = 0; nt < 4; ++nt)
            acc2[mt2][nt] = __builtin_amdgcn_mfma_f32_16x16x32_bf16(w2[nt], hf, acc2[mt2][nt], 0, 0, 0);
        }
      }
    }
    __syncthreads();
  }

  // ---- residual add + store: contiguous float4 per lane ----
  #pragma unroll
  for (int mt2 = 0; mt2 < 2; ++mt2) {
    #pragma unroll
    for (int nt = 0; nt < 4; ++nt) {
      size_t idx = (size_t)(m0 + (wm * 2 + mt2) * 16 + l15) * 256 + (wn * 4 + nt) * 16 + quad * 4;
      float4 r = *(const float4*)(xin + idx);
      float4 o;
      o.x = r.x + acc2[mt2][nt][0];
      o.y = r.y + acc2[mt2][nt][1];
      o.z = r.z + acc2[mt2][nt][2];
      o.w = r.w + acc2[mt2][nt][3];
      *(float4*)(out + idx) = o;
    }
  }
}

// ---------------- fused window attention v3 (unchanged) ---------------------
__global__ __launch_bounds__(256, 4) void attn_v3(const u16* __restrict__ qkv,
                                                  const u16* __restrict__ biasb,
                                                  int layer, u16* __restrict__ aout) {
  __shared__ u16 Klds[256 * 32];
  __shared__ u16 Vt[32 * 264];
  __shared__ u16 Plds[4][16 * 40];
  int bid = blockIdx.x;
  int lw = ((bid & 7) << 7) | (bid >> 3);   // XCD swizzle
  int w = lw >> 3, h = lw & 7;
  int tid = threadIdx.x;

  {
    const uint4* kp = (const uint4*)(qkv + ((size_t)(w * 256 + tid)) * 768 + 256 + h * 32);
    uint4* kd = (uint4*)&Klds[tid * 32];
    kd[0] = kp[0]; kd[1] = kp[1]; kd[2] = kp[2]; kd[3] = kp[3];
    const uint4* vp = (const uint4*)(qkv + ((size_t)(w * 256 + tid)) * 768 + 512 + h * 32);
    u16 vt[32];
    *(uint4*)&vt[0]  = vp[0];
    *(uint4*)&vt[8]  = vp[1];
    *(uint4*)&vt[16] = vp[2];
    *(uint4*)&vt[24] = vp[3];
    #pragma unroll
    for (int d = 0; d < 32; ++d) Vt[d * 264 + tid] = vt[d];
  }
  __syncthreads();

  int wv = tid >> 6, lane = tid & 63, quad = lane >> 4, l15 = lane & 15;
  int wi = w & 15, wr = wi >> 2, wc = wi & 3;
  const bool masked = (layer != 0) && (wr == 3 || wc == 3);
  int rcj = (wc == 3) ? (l15 < 8 ? 1 : 2) : 0;

  #pragma unroll
  for (int mt = 0; mt < 4; ++mt) {
    int mslot = wv * 4 + mt;
    int m0 = mslot * 16;
    short8 aq = *(const short8*)(qkv + ((size_t)(w * 256 + m0 + l15)) * 768 + h * 32 + quad * 8);
    const u16* bmt = biasb + ((size_t)layer << 19) + ((size_t)h << 16) + (size_t)mslot * 4096;
    f32x4 c[16];
    #pragma unroll
    for (int k = 0; k < 8; ++k) {
      short8 bv = *(const short8*)(bmt + k * 512 + lane * 8);
      #pragma unroll
      for (int r = 0; r < 4; ++r) {
        c[2 * k][r]     = bf2f((u16)bv[r]);
        c[2 * k + 1][r] = bf2f((u16)bv[4 + r]);
      }
    }
    #pragma unroll
    for (int nt = 0; nt < 16; ++nt) {
      short8 bk = *(const short8*)&Klds[(nt * 16 + l15) * 32 + quad * 8];
      c[nt] = __builtin_amdgcn_mfma_f32_16x16x32_bf16(aq, bk, c[nt], 0, 0, 0);
    }
    if (masked) {
      int regi = ((wr == 3) ? (mslot < 8 ? 1 : 2) : 0) * 3 +
                 ((wc == 3) ? (quad < 2 ? 1 : 2) : 0);
      #pragma unroll
      for (int nt = 0; nt < 16; ++nt) {
        int regj = ((wr == 3) ? (nt < 8 ? 1 : 2) : 0) * 3 + rcj;
        float madd = (regi != regj) ? -100.f : 0.f;
        #pragma unroll
        for (int r = 0; r < 4; ++r) c[nt][r] += madd;
      }
    }
    float pm[4] = {-1e30f, -1e30f, -1e30f, -1e30f};
    #pragma unroll
    for (int nt = 0; nt < 16; ++nt)
      #pragma unroll
      for (int r = 0; r < 4; ++r) pm[r] = fmaxf(pm[r], c[nt][r]);
    #pragma unroll
    for (int r = 0; r < 4; ++r) {
      pm[r] = fmaxf(pm[r], __shfl_xor(pm[r], 1, 64));
      pm[r] = fmaxf(pm[r], __shfl_xor(pm[r], 2, 64));
      pm[r] = fmaxf(pm[r], __shfl_xor(pm[r], 4, 64));
      pm[r] = fmaxf(pm[r], __shfl_xor(pm[r], 8, 64));
    }
    float psum[4] = {0.f, 0.f, 0.f, 0.f};
    #pragma unroll
    for (int nt = 0; nt < 16; ++nt)
      #pragma unroll
      for (int r = 0; r < 4; ++r) {
        float e = __expf(c[nt][r] - pm[r]);
        c[nt][r] = e;
        psum[r] += e;
      }
    #pragma unroll
    for (int r = 0; r < 4; ++r) {
      psum[r] += __shfl_xor(psum[r], 1, 64);
      psum[r] += __shfl_xor(psum[r], 2, 64);
      psum[r] += __shfl_xor(psum[r], 4, 64);
      psum[r] += __shfl_xor(psum[r], 8, 64);
    }
    f32x4 o0 = {0.f, 0.f, 0.f, 0.f}, o1 = {0.f, 0.f, 0.f, 0.f};
    #pragma unroll
    for (int kk = 0; kk < 8; ++kk) {
      #pragma unroll
      for (int r = 0; r < 4; ++r) {
        Plds[wv][(quad * 4 + r) * 40 + l15] = f2bf(c[2 * kk][r]);
        Plds[wv][(quad * 4 + r) * 40 + 16 + l15] = f2bf(c[2 * kk + 1][r]);
      }
      short8 ap = *(const short8*)&Plds[wv][l15 * 40 + quad * 8];
      short8 bv0 = *(const short8*)&Vt[l15 * 264 + kk * 32 + quad * 8];
      short8 bv1 = *(const short8*)&Vt[(16 + l15) * 264 + kk * 32 + quad * 8];
      o0 = __builtin_amdgcn_mfma_f32_16x16x32_bf16(ap, bv0, o0, 0, 0, 0);
      o1 = __builtin_amdgcn_mfma_f32_16x16x32_bf16(ap, bv1, o1, 0, 0, 0);
    }
    #pragma unroll
    for (int r = 0; r < 4; ++r) {
      float inv = 1.f / psum[r];
      size_t row = (size_t)(w * 256 + m0 + quad * 4 + r);
      aout[row * 256 + h * 32 + l15] = f2bf(o0[r] * inv);
      aout[row * 256 + h * 32 + 16 + l15] = f2bf(o1[r] * inv);
    }
  }
}

// ----------------------------------------------------------------------------
extern "C" void kernel_launch(void* const* d_in, const int* in_sizes, int n_in,
                              void* d_out, int out_size, void* d_ws, size_t ws_size,
                              hipStream_t stream) {
  const float* x      = (const float*)d_in[0];
  const float* ln1_g  = (const float*)d_in[1];
  const float* ln1_b  = (const float*)d_in[2];
  const float* qkv_w  = (const float*)d_in[3];
  const float* qkv_b  = (const float*)d_in[4];
  const float* rpb    = (const float*)d_in[5];
  const float* proj_w = (const float*)d_in[6];
  const float* proj_b = (const float*)d_in[7];
  const float* ln2_g  = (const float*)d_in[8];
  const float* ln2_b  = (const float*)d_in[9];
  const float* fc1_w  = (const float*)d_in[10];
  const float* fc1_b  = (const float*)d_in[11];
  const float* fc2_w  = (const float*)d_in[12];
  const float* fc2_b  = (const float*)d_in[13];
  const int*   rpi    = (const int*)d_in[15];

  char* ws = (char*)d_ws;
  size_t off = 0;
  auto alloc = [&](size_t bytes) { void* p = ws + off; off += (bytes + 255) & ~(size_t)255; return p; };
  float* x_cur   = (float*)alloc((size_t)32768 * 256 * 4);   // residual stream
  u16* sbuf      = (u16*)alloc((size_t)32768 * 256 * 2);     // wins -> attn_out
  u16* qkvb      = (u16*)alloc((size_t)32768 * 768 * 2);
  u16* biasb     = (u16*)alloc((size_t)2 * 8 * 65536 * 2);   // pre-swizzled bf16 bias
  u16* qkvF      = (u16*)alloc((size_t)2 * 196608 * 2);      // qkv B-fragments
  u16* projF     = (u16*)alloc((size_t)2 * 65536 * 2);       // proj B-fragments
  u16* W1f       = (u16*)alloc((size_t)2 * 262144 * 2);      // fc1 B-fragments
  u16* W2f       = (u16*)alloc((size_t)2 * 262144 * 2);      // fc2 B-fragments

  // prep
  wswizB<<<192, 256, 0, stream>>>(qkv_w, qkvF, 256, 768);
  wswizB<<<64, 256, 0, stream>>>(proj_w, projF, 256, 256);
  wswiz1<<<256, 256, 0, stream>>>(fc1_w, W1f);
  wswiz2<<<256, 256, 0, stream>>>(fc2_w, W2f);
  bias_gb<<<512, 256, 0, stream>>>(rpb, rpi, biasb);

  for (int i = 0; i < 2; ++i) {
    int shift = i ? 8 : 0;
    const float* xin = i ? x_cur : x;

    ln_part<<<8192, 256, 0, stream>>>(xin, ln1_g + i * 256, ln1_b + i * 256, sbuf, shift);

    EpiParams ep{};
    ep.bias = qkv_b + i * 768; ep.obf = qkvb; ep.qscale = 0.17677669529663687f;
    gemm_fk2<<<dim3(3, 256), 512, 0, stream>>>(sbuf, qkvF + (size_t)i * 196608, 768, ep);

    attn_v3<<<1024, 256, 0, stream>>>(qkvb, biasb, i, sbuf);

    ep = EpiParams{};
    ep.bias = proj_b + i * 256; ep.of32 = x_cur; ep.resid = xin; ep.shift = shift;
    gemm_fk<2><<<dim3(2, 256), 512, 0, stream>>>(sbuf, projF + (size_t)i * 65536, 256, ep);

    fused_mlp<<<512, 512, 0, stream>>>(x_cur, ln2_g + i * 256, ln2_b + i * 256,
                                       W1f + (size_t)i * 262144, W2f + (size_t)i * 262144,
                                       fc1_b + i * 1024, fc2_b + i * 256,
                                       (i == 1) ? (float*)d_out : x_cur);
  }
}

// Round 6
// 423.126 us; speedup vs baseline: 1.0258x; 1.0258x over previous
//
#include <hip/hip_runtime.h>

typedef unsigned short u16;
typedef __attribute__((ext_vector_type(8))) short short8;
typedef __attribute__((ext_vector_type(4))) float f32x4;

#define GLDS16(gp, sp) __builtin_amdgcn_global_load_lds( \
    (const __attribute__((address_space(1))) void*)(gp),  \
    (__attribute__((address_space(3))) void*)(sp), 16, 0, 0)

__device__ __forceinline__ u16 f2bf(float f) {
  union { float f; unsigned u; } x; x.f = f;
  unsigned r = (x.u + 0x7fffu + ((x.u >> 16) & 1u)) >> 16;  // RNE
  return (u16)r;
}
__device__ __forceinline__ float bf2f(u16 v) {
  union { unsigned u; float f; } x; x.u = ((unsigned)v) << 16; return x.f;
}
__device__ __forceinline__ unsigned cvt_pk_bf16(float lo, float hi) {
  unsigned r;
  asm("v_cvt_pk_bf16_f32 %0, %1, %2" : "=v"(r) : "v"(lo), "v"(hi));
  return r;
}

// ------- generic weight -> bf16 MFMA B-fragment order --------------------
__global__ __launch_bounds__(256) void wswizB(const float* __restrict__ W,
                                              u16* __restrict__ Wf, int K, int N) {
  int tid = blockIdx.x * 256 + threadIdx.x;
  int Kt = K >> 5, Nt = N >> 4;
  int per = Nt * Kt * 64;
  if (tid >= 2 * per) return;
  int l = tid >= per;
  int rem = tid - l * per;
  int nb = rem / (Kt * 64);
  int rem2 = rem - nb * Kt * 64;
  int ks = rem2 >> 6, lane = rem2 & 63;
  int n = nb * 16 + (lane & 15);
  u16 o[8];
  #pragma unroll
  for (int e = 0; e < 8; ++e) {
    int k = ks * 32 + ((lane >> 4) << 3) + e;
    o[e] = f2bf(W[((size_t)l * K + k) * N + n]);
  }
  *(uint4*)(Wf + ((size_t)tid << 3)) = *(uint4*)o;
}

// ------- fc1 weights -> B-fragment order: W1f[l][hc(8)][ks(8)][ntile(8)][lane][8]
__global__ __launch_bounds__(256) void wswiz1(const float* __restrict__ W,
                                              u16* __restrict__ Wf) {
  int tid = blockIdx.x * 256 + threadIdx.x;  // [0, 65536)
  int lane = tid & 63, nt = (tid >> 6) & 7, ks = (tid >> 9) & 7,
      hc = (tid >> 12) & 7, l = tid >> 15;
  int n = hc * 128 + nt * 16 + (lane & 15);
  u16 o[8];
  #pragma unroll
  for (int e = 0; e < 8; ++e) {
    int k = ks * 32 + ((lane >> 4) << 3) + e;
    o[e] = f2bf(W[((size_t)l * 256 + k) * 1024 + n]);
  }
  *(uint4*)(Wf + ((size_t)tid << 3)) = *(uint4*)o;
}

// ------- fc2 weights -> B-fragment order: W2f[l][hc(8)][ks(4)][ntile(16)][lane][8]
__global__ __launch_bounds__(256) void wswiz2(const float* __restrict__ W,
                                              u16* __restrict__ Wf) {
  int tid = blockIdx.x * 256 + threadIdx.x;  // [0, 65536)
  int lane = tid & 63, nt = (tid >> 6) & 15, ks = (tid >> 10) & 3,
      hc = (tid >> 12) & 7, l = tid >> 15;
  int n = nt * 16 + (lane & 15);
  u16 o[8];
  #pragma unroll
  for (int e = 0; e < 8; ++e) {
    int k = hc * 128 + ks * 32 + ((lane >> 4) << 3) + e;
    o[e] = f2bf(W[((size_t)l * 1024 + k) * 256 + n]);
  }
  *(uint4*)(Wf + ((size_t)tid << 3)) = *(uint4*)o;
}

// ------- rel-pos bias gather, bf16, pre-swizzled to MFMA C-layout ------------
__global__ __launch_bounds__(256) void bias_gb(const float* __restrict__ rpb,
                                               const int* __restrict__ rpi,
                                               u16* __restrict__ biasb) {
  int tid = blockIdx.x * 256 + threadIdx.x;  // [0, 2*65536)
  if (tid >= 131072) return;
  int l = tid >> 16, cid = tid & 65535;
  int lane = cid & 63, k = (cid >> 6) & 7, mslot = (cid >> 9) & 15, h = cid >> 13;
  u16 o[8];
  #pragma unroll
  for (int e = 0; e < 8; ++e) {
    int nt = 2 * k + (e >> 2), r = e & 3;
    int i = mslot * 16 + ((lane >> 4) << 2) + r;
    int j = nt * 16 + (lane & 15);
    int idx = rpi[i * 256 + j];
    o[e] = f2bf(rpb[((size_t)l * 961 + idx) * 8 + h]);
  }
  *(uint4*)(biasb + ((size_t)tid << 3)) = *(uint4*)o;
}

// ---------------- LN1 + shift + window partition -> bf16 wins ---------------
__global__ __launch_bounds__(256) void ln_part(const float* __restrict__ x,
                                               const float* __restrict__ g,
                                               const float* __restrict__ b,
                                               u16* __restrict__ out, int shift) {
  int wv = threadIdx.x >> 6, lane = threadIdx.x & 63;
  int wtok = blockIdx.x * 4 + wv;
  int w = wtok >> 8, t = wtok & 255;
  int bimg = w >> 4, wi = w & 15;
  int ph = (((wi >> 2) << 4) + (t >> 4) + shift) & 63;
  int pw = (((wi & 3) << 4) + (t & 15) + shift) & 63;
  const float4 v = *(const float4*)(x + ((size_t)((bimg * 64 + ph) * 64 + pw)) * 256 + lane * 4);
  float s = v.x + v.y + v.z + v.w;
  float sq = v.x * v.x + v.y * v.y + v.z * v.z + v.w * v.w;
  #pragma unroll
  for (int m = 1; m < 64; m <<= 1) { s += __shfl_xor(s, m, 64); sq += __shfl_xor(sq, m, 64); }
  float mean = s * (1.f / 256.f);
  float var = sq * (1.f / 256.f) - mean * mean;
  float rs = rsqrtf(var + 1e-5f);
  float4 gg = *(const float4*)(g + lane * 4);
  float4 bb = *(const float4*)(b + lane * 4);
  uint2 pk;
  pk.x = cvt_pk_bf16((v.x - mean) * rs * gg.x + bb.x,
                     (v.y - mean) * rs * gg.y + bb.y);
  pk.y = cvt_pk_bf16((v.z - mean) * rs * gg.z + bb.z,
                     (v.w - mean) * rs * gg.w + bb.w);
  *(uint2*)(out + (size_t)wtok * 256 + lane * 4) = pk;
}

struct EpiParams {
  const float* bias;
  u16* obf;
  float* of32;
  const float* resid;
  int shift;
  float qscale;
};

// ---------------- GEMM v2: 128x256 tile, full-K staged, A-read reuse x4 -----
__global__ __launch_bounds__(512, 2) void gemm_fk2(const u16* __restrict__ A,
                                                   const u16* __restrict__ Wf,
                                                   int N, EpiParams ep) {
  __shared__ u16 As[8][128][32];   // 64 KB
  int tid = threadIdx.x;
  int n0 = blockIdx.x * 256, m0 = blockIdx.y * 128;
  int wv = tid >> 6, lane = tid & 63, quad = lane >> 4, l15 = lane & 15;
  int wm = wv & 1, wn = wv >> 1;   // wn in 0..3

  #pragma unroll
  for (int i = 0; i < 8; ++i) {
    int c = i * 512 + tid;
    int kb = c >> 9, rc = c & 511;
    int row = rc >> 2, kc = (rc & 3) * 8;
    GLDS16(A + (size_t)(m0 + row) * 256 + kb * 32 + kc, &As[kb][row][kc]);
  }
  __syncthreads();

  f32x4 acc[4][4] = {};
  #pragma unroll
  for (int kb = 0; kb < 8; ++kb) {
    short8 bf[4];
    #pragma unroll
    for (int nt = 0; nt < 4; ++nt) {
      size_t ntile = (size_t)(blockIdx.x * 16 + wn * 4 + nt);
      bf[nt] = *(const short8*)(Wf + ((ntile * 8 + kb) * 64 + lane) * 8);
    }
    #pragma unroll
    for (int mt = 0; mt < 4; ++mt) {
      short8 af = *(const short8*)&As[kb][wm * 64 + mt * 16 + l15][quad * 8];
      #pragma unroll
      for (int nt = 0; nt < 4; ++nt)
        acc[mt][nt] = __builtin_amdgcn_mfma_f32_16x16x32_bf16(af, bf[nt], acc[mt][nt], 0, 0, 0);
    }
  }

  #pragma unroll
  for (int mt = 0; mt < 4; ++mt) {
    #pragma unroll
    for (int nt = 0; nt < 4; ++nt) {
      #pragma unroll
      for (int r = 0; r < 4; ++r) {
        int grow = m0 + wm * 64 + mt * 16 + quad * 4 + r;
        int gcol = n0 + wn * 64 + nt * 16 + l15;
        float v = acc[mt][nt][r] + ep.bias[gcol];
        if (gcol < 256) v *= ep.qscale;
        ep.obf[(size_t)grow * N + gcol] = f2bf(v);
      }
    }
  }
}

// ---------------- GEMM, full-K staged (round-7, used for proj) --------------
template <int EPI>
__global__ __launch_bounds__(512, 2) void gemm_fk(const u16* __restrict__ A,
                                                  const u16* __restrict__ Wf,
                                                  int N, EpiParams ep) {
  __shared__ u16 As[8][128][32];   // 64 KB
  int tid = threadIdx.x;
  int n0 = blockIdx.x * 128, m0 = blockIdx.y * 128;
  int wv = tid >> 6, lane = tid & 63, quad = lane >> 4, l15 = lane & 15;
  int wm = wv & 1, wn = wv >> 1;

  #pragma unroll
  for (int i = 0; i < 8; ++i) {
    int c = i * 512 + tid;
    int kb = c >> 9, rc = c & 511;
    int row = rc >> 2, kc = (rc & 3) * 8;
    GLDS16(A + (size_t)(m0 + row) * 256 + kb * 32 + kc, &As[kb][row][kc]);
  }
  __syncthreads();

  f32x4 acc[4][2] = {};
  #pragma unroll
  for (int kb = 0; kb < 8; ++kb) {
    short8 bf[2];
    #pragma unroll
    for (int nt = 0; nt < 2; ++nt) {
      size_t ntile = (size_t)(blockIdx.x * 8 + wn * 2 + nt);
      bf[nt] = *(const short8*)(Wf + ((ntile * 8 + kb) * 64 + lane) * 8);
    }
    #pragma unroll
    for (int mt = 0; mt < 4; ++mt) {
      short8 af = *(const short8*)&As[kb][wm * 64 + mt * 16 + l15][quad * 8];
      #pragma unroll
      for (int nt = 0; nt < 2; ++nt)
        acc[mt][nt] = __builtin_amdgcn_mfma_f32_16x16x32_bf16(af, bf[nt], acc[mt][nt], 0, 0, 0);
    }
  }

  #pragma unroll
  for (int mt = 0; mt < 4; ++mt) {
    #pragma unroll
    for (int nt = 0; nt < 2; ++nt) {
      #pragma unroll
      for (int r = 0; r < 4; ++r) {
        int grow = m0 + wm * 64 + mt * 16 + quad * 4 + r;
        int gcol = n0 + wn * 32 + nt * 16 + l15;
        float v = acc[mt][nt][r] + ep.bias[gcol];
        if constexpr (EPI == 0) {
          if (gcol < 256) v *= ep.qscale;
          ep.obf[(size_t)grow * N + gcol] = f2bf(v);
        } else {
          int w_ = grow >> 8, t = grow & 255, wi = w_ & 15;
          int ph = (((wi >> 2) << 4) + (t >> 4) + ep.shift) & 63;
          int pw = (((wi & 3) << 4) + (t & 15) + ep.shift) & 63;
          size_t pix = (size_t)(((w_ >> 4) * 64 + ph) * 64 + pw);
          ep.of32[pix * 256 + gcol] = ep.resid[pix * 256 + gcol] + v;
        }
      }
    }
  }
}

// ---------------- fused MLP v9: exact v4 structure (best measured, 56.9us)
// + s_setprio(1) around MFMA clusters (T5: the 2 co-resident blocks sit in
// different phases -> role diversity -> scheduler can favor MFMA-phase waves).
// v5-v8 post-mortems: kernel is latency-bound (all pipes <30%); LDS-read
// halving (v8) and packed stores (v6) were neutral-to-negative. Revert.
// (Round-5 bench was an infra failure — resubmitting unchanged.)
__global__ __launch_bounds__(512, 4) void fused_mlp(const float* __restrict__ xin,
                                                    const float* __restrict__ g,
                                                    const float* __restrict__ b,
                                                    const u16* __restrict__ W1f,
                                                    const u16* __restrict__ W2f,
                                                    const float* __restrict__ b1p,
                                                    const float* __restrict__ b2p,
                                                    float* __restrict__ out) {
  __shared__ u16 Zs[64 * 264];
  __shared__ u16 Hs[2][64 * 136];
  int tid = threadIdx.x, wv = tid >> 6, lane = tid & 63;
  int quad = lane >> 4, l15 = lane & 15;
  int m0 = blockIdx.x * 64;

  float4 gg = *(const float4*)(g + lane * 4);
  float4 bb = *(const float4*)(b + lane * 4);
  #pragma unroll
  for (int rr = 0; rr < 8; ++rr) {
    int row = wv * 8 + rr;
    const float4 v = *(const float4*)(xin + (size_t)(m0 + row) * 256 + lane * 4);
    float s = v.x + v.y + v.z + v.w;
    float sq = v.x * v.x + v.y * v.y + v.z * v.z + v.w * v.w;
    #pragma unroll
    for (int m = 1; m < 64; m <<= 1) { s += __shfl_xor(s, m, 64); sq += __shfl_xor(sq, m, 64); }
    float mean = s * (1.f / 256.f);
    float var = sq * (1.f / 256.f) - mean * mean;
    float rs = rsqrtf(var + 1e-5f);
    u16 o0 = f2bf((v.x - mean) * rs * gg.x + bb.x);
    u16 o1 = f2bf((v.y - mean) * rs * gg.y + bb.y);
    u16 o2 = f2bf((v.z - mean) * rs * gg.z + bb.z);
    u16 o3 = f2bf((v.w - mean) * rs * gg.w + bb.w);
    uint2 pk; pk.x = (unsigned)o0 | ((unsigned)o1 << 16); pk.y = (unsigned)o2 | ((unsigned)o3 << 16);
    *(uint2*)&Zs[row * 264 + lane * 4] = pk;
  }
  __syncthreads();

  f32x4 acc2[4][2];
  #pragma unroll
  for (int nt = 0; nt < 2; ++nt) {
    float b2 = b2p[wv * 32 + nt * 16 + l15];
    #pragma unroll
    for (int mt = 0; mt < 4; ++mt)
      #pragma unroll
      for (int r = 0; r < 4; ++r) acc2[mt][nt][r] = b2;
  }

  for (int hp = 0; hp < 4; ++hp) {
    int hcA = 2 * hp, hcB = 2 * hp + 1;
    // ---- phase A for BOTH chunks, sharing Zs fragment reads
    f32x4 acc1a[4], acc1b[4];
    {
      float b1a = b1p[hcA * 128 + wv * 16 + l15];
      float b1b = b1p[hcB * 128 + wv * 16 + l15];
      #pragma unroll
      for (int mt = 0; mt < 4; ++mt)
        #pragma unroll
        for (int r = 0; r < 4; ++r) { acc1a[mt][r] = b1a; acc1b[mt][r] = b1b; }
    }
    #pragma unroll
    for (int ks = 0; ks < 8; ++ks) {
      short8 bfa = *(const short8*)(W1f + ((((size_t)hcA * 8 + ks) * 8 + wv) * 64 + lane) * 8);
      short8 bfb = *(const short8*)(W1f + ((((size_t)hcB * 8 + ks) * 8 + wv) * 64 + lane) * 8);
      __builtin_amdgcn_s_setprio(1);
      #pragma unroll
      for (int mt = 0; mt < 4; ++mt) {
        short8 af = *(const short8*)&Zs[(mt * 16 + l15) * 264 + ks * 32 + quad * 8];
        acc1a[mt] = __builtin_amdgcn_mfma_f32_16x16x32_bf16(af, bfa, acc1a[mt], 0, 0, 0);
        acc1b[mt] = __builtin_amdgcn_mfma_f32_16x16x32_bf16(af, bfb, acc1b[mt], 0, 0, 0);
      }
      __builtin_amdgcn_s_setprio(0);
    }
    // ---- gelu + transpose both chunks
    #pragma unroll
    for (int mt = 0; mt < 4; ++mt)
      #pragma unroll
      for (int r = 0; r < 4; ++r) {
        float va = acc1a[mt][r];
        float ia = va * (1.f + 0.044715f * va * va);
        float ea = __expf(-1.5957691216057308f * ia);
        Hs[0][(mt * 16 + quad * 4 + r) * 136 + wv * 16 + l15] =
            f2bf(va * __builtin_amdgcn_rcpf(1.f + ea));
        float vb = acc1b[mt][r];
        float ib = vb * (1.f + 0.044715f * vb * vb);
        float eb = __expf(-1.5957691216057308f * ib);
        Hs[1][(mt * 16 + quad * 4 + r) * 136 + wv * 16 + l15] =
            f2bf(vb * __builtin_amdgcn_rcpf(1.f + eb));
      }
    __syncthreads();
    // ---- phase B over both chunks
    #pragma unroll
    for (int buf = 0; buf < 2; ++buf) {
      int hc = 2 * hp + buf;
      #pragma unroll
      for (int ks = 0; ks < 4; ++ks) {
        short8 bf2[2];
        #pragma unroll
        for (int nt = 0; nt < 2; ++nt)
          bf2[nt] = *(const short8*)(W2f + ((((size_t)hc * 4 + ks) * 16 + wv * 2 + nt) * 64 + lane) * 8);
        __builtin_amdgcn_s_setprio(1);
        #pragma unroll
        for (int mt = 0; mt < 4; ++mt) {
          short8 af2 = *(const short8*)&Hs[buf][(mt * 16 + l15) * 136 + ks * 32 + quad * 8];
          #pragma unroll
          for (int nt = 0; nt < 2; ++nt)
            acc2[mt][nt] = __builtin_amdgcn_mfma_f32_16x16x32_bf16(af2, bf2[nt], acc2[mt][nt], 0, 0, 0);
        }
        __builtin_amdgcn_s_setprio(0);
      }
    }
    __syncthreads();
  }

  #pragma unroll
  for (int mt = 0; mt < 4; ++mt)
    #pragma unroll
    for (int nt = 0; nt < 2; ++nt)
      #pragma unroll
      for (int r = 0; r < 4; ++r) {
        size_t idx = (size_t)(m0 + mt * 16 + quad * 4 + r) * 256 + wv * 32 + nt * 16 + l15;
        out[idx] = xin[idx] + acc2[mt][nt][r];
      }
}

// ---------------- fused window attention v3 (unchanged) ---------------------
__global__ __launch_bounds__(256, 4) void attn_v3(const u16* __restrict__ qkv,
                                                  const u16* __restrict__ biasb,
                                                  int layer, u16* __restrict__ aout) {
  __shared__ u16 Klds[256 * 32];
  __shared__ u16 Vt[32 * 264];
  __shared__ u16 Plds[4][16 * 40];
  int bid = blockIdx.x;
  int lw = ((bid & 7) << 7) | (bid >> 3);   // XCD swizzle
  int w = lw >> 3, h = lw & 7;
  int tid = threadIdx.x;

  {
    const uint4* kp = (const uint4*)(qkv + ((size_t)(w * 256 + tid)) * 768 + 256 + h * 32);
    uint4* kd = (uint4*)&Klds[tid * 32];
    kd[0] = kp[0]; kd[1] = kp[1]; kd[2] = kp[2]; kd[3] = kp[3];
    const uint4* vp = (const uint4*)(qkv + ((size_t)(w * 256 + tid)) * 768 + 512 + h * 32);
    u16 vt[32];
    *(uint4*)&vt[0]  = vp[0];
    *(uint4*)&vt[8]  = vp[1];
    *(uint4*)&vt[16] = vp[2];
    *(uint4*)&vt[24] = vp[3];
    #pragma unroll
    for (int d = 0; d < 32; ++d) Vt[d * 264 + tid] = vt[d];
  }
  __syncthreads();

  int wv = tid >> 6, lane = tid & 63, quad = lane >> 4, l15 = lane & 15;
  int wi = w & 15, wr = wi >> 2, wc = wi & 3;
  const bool masked = (layer != 0) && (wr == 3 || wc == 3);
  int rcj = (wc == 3) ? (l15 < 8 ? 1 : 2) : 0;

  #pragma unroll
  for (int mt = 0; mt < 4; ++mt) {
    int mslot = wv * 4 + mt;
    int m0 = mslot * 16;
    short8 aq = *(const short8*)(qkv + ((size_t)(w * 256 + m0 + l15)) * 768 + h * 32 + quad * 8);
    const u16* bmt = biasb + ((size_t)layer << 19) + ((size_t)h << 16) + (size_t)mslot * 4096;
    f32x4 c[16];
    #pragma unroll
    for (int k = 0; k < 8; ++k) {
      short8 bv = *(const short8*)(bmt + k * 512 + lane * 8);
      #pragma unroll
      for (int r = 0; r < 4; ++r) {
        c[2 * k][r]     = bf2f((u16)bv[r]);
        c[2 * k + 1][r] = bf2f((u16)bv[4 + r]);
      }
    }
    #pragma unroll
    for (int nt = 0; nt < 16; ++nt) {
      short8 bk = *(const short8*)&Klds[(nt * 16 + l15) * 32 + quad * 8];
      c[nt] = __builtin_amdgcn_mfma_f32_16x16x32_bf16(aq, bk, c[nt], 0, 0, 0);
    }
    if (masked) {
      int regi = ((wr == 3) ? (mslot < 8 ? 1 : 2) : 0) * 3 +
                 ((wc == 3) ? (quad < 2 ? 1 : 2) : 0);
      #pragma unroll
      for (int nt = 0; nt < 16; ++nt) {
        int regj = ((wr == 3) ? (nt < 8 ? 1 : 2) : 0) * 3 + rcj;
        float madd = (regi != regj) ? -100.f : 0.f;
        #pragma unroll
        for (int r = 0; r < 4; ++r) c[nt][r] += madd;
      }
    }
    float pm[4] = {-1e30f, -1e30f, -1e30f, -1e30f};
    #pragma unroll
    for (int nt = 0; nt < 16; ++nt)
      #pragma unroll
      for (int r = 0; r < 4; ++r) pm[r] = fmaxf(pm[r], c[nt][r]);
    #pragma unroll
    for (int r = 0; r < 4; ++r) {
      pm[r] = fmaxf(pm[r], __shfl_xor(pm[r], 1, 64));
      pm[r] = fmaxf(pm[r], __shfl_xor(pm[r], 2, 64));
      pm[r] = fmaxf(pm[r], __shfl_xor(pm[r], 4, 64));
      pm[r] = fmaxf(pm[r], __shfl_xor(pm[r], 8, 64));
    }
    float psum[4] = {0.f, 0.f, 0.f, 0.f};
    #pragma unroll
    for (int nt = 0; nt < 16; ++nt)
      #pragma unroll
      for (int r = 0; r < 4; ++r) {
        float e = __expf(c[nt][r] - pm[r]);
        c[nt][r] = e;
        psum[r] += e;
      }
    #pragma unroll
    for (int r = 0; r < 4; ++r) {
      psum[r] += __shfl_xor(psum[r], 1, 64);
      psum[r] += __shfl_xor(psum[r], 2, 64);
      psum[r] += __shfl_xor(psum[r], 4, 64);
      psum[r] += __shfl_xor(psum[r], 8, 64);
    }
    f32x4 o0 = {0.f, 0.f, 0.f, 0.f}, o1 = {0.f, 0.f, 0.f, 0.f};
    #pragma unroll
    for (int kk = 0; kk < 8; ++kk) {
      #pragma unroll
      for (int r = 0; r < 4; ++r) {
        Plds[wv][(quad * 4 + r) * 40 + l15] = f2bf(c[2 * kk][r]);
        Plds[wv][(quad * 4 + r) * 40 + 16 + l15] = f2bf(c[2 * kk + 1][r]);
      }
      short8 ap = *(const short8*)&Plds[wv][l15 * 40 + quad * 8];
      short8 bv0 = *(const short8*)&Vt[l15 * 264 + kk * 32 + quad * 8];
      short8 bv1 = *(const short8*)&Vt[(16 + l15) * 264 + kk * 32 + quad * 8];
      o0 = __builtin_amdgcn_mfma_f32_16x16x32_bf16(ap, bv0, o0, 0, 0, 0);
      o1 = __builtin_amdgcn_mfma_f32_16x16x32_bf16(ap, bv1, o1, 0, 0, 0);
    }
    #pragma unroll
    for (int r = 0; r < 4; ++r) {
      float inv = 1.f / psum[r];
      size_t row = (size_t)(w * 256 + m0 + quad * 4 + r);
      aout[row * 256 + h * 32 + l15] = f2bf(o0[r] * inv);
      aout[row * 256 + h * 32 + 16 + l15] = f2bf(o1[r] * inv);
    }
  }
}

// ----------------------------------------------------------------------------
extern "C" void kernel_launch(void* const* d_in, const int* in_sizes, int n_in,
                              void* d_out, int out_size, void* d_ws, size_t ws_size,
                              hipStream_t stream) {
  const float* x      = (const float*)d_in[0];
  const float* ln1_g  = (const float*)d_in[1];
  const float* ln1_b  = (const float*)d_in[2];
  const float* qkv_w  = (const float*)d_in[3];
  const float* qkv_b  = (const float*)d_in[4];
  const float* rpb    = (const float*)d_in[5];
  const float* proj_w = (const float*)d_in[6];
  const float* proj_b = (const float*)d_in[7];
  const float* ln2_g  = (const float*)d_in[8];
  const float* ln2_b  = (const float*)d_in[9];
  const float* fc1_w  = (const float*)d_in[10];
  const float* fc1_b  = (const float*)d_in[11];
  const float* fc2_w  = (const float*)d_in[12];
  const float* fc2_b  = (const float*)d_in[13];
  const int*   rpi    = (const int*)d_in[15];

  char* ws = (char*)d_ws;
  size_t off = 0;
  auto alloc = [&](size_t bytes) { void* p = ws + off; off += (bytes + 255) & ~(size_t)255; return p; };
  float* x_cur   = (float*)alloc((size_t)32768 * 256 * 4);   // residual stream
  u16* sbuf      = (u16*)alloc((size_t)32768 * 256 * 2);     // wins -> attn_out
  u16* qkvb      = (u16*)alloc((size_t)32768 * 768 * 2);
  u16* biasb     = (u16*)alloc((size_t)2 * 8 * 65536 * 2);   // pre-swizzled bf16 bias
  u16* qkvF      = (u16*)alloc((size_t)2 * 196608 * 2);      // qkv B-fragments
  u16* projF     = (u16*)alloc((size_t)2 * 65536 * 2);       // proj B-fragments
  u16* W1f       = (u16*)alloc((size_t)2 * 262144 * 2);      // fc1 B-fragments
  u16* W2f       = (u16*)alloc((size_t)2 * 262144 * 2);      // fc2 B-fragments

  // prep
  wswizB<<<192, 256, 0, stream>>>(qkv_w, qkvF, 256, 768);
  wswizB<<<64, 256, 0, stream>>>(proj_w, projF, 256, 256);
  wswiz1<<<256, 256, 0, stream>>>(fc1_w, W1f);
  wswiz2<<<256, 256, 0, stream>>>(fc2_w, W2f);
  bias_gb<<<512, 256, 0, stream>>>(rpb, rpi, biasb);

  for (int i = 0; i < 2; ++i) {
    int shift = i ? 8 : 0;
    const float* xin = i ? x_cur : x;

    ln_part<<<8192, 256, 0, stream>>>(xin, ln1_g + i * 256, ln1_b + i * 256, sbuf, shift);

    EpiParams ep{};
    ep.bias = qkv_b + i * 768; ep.obf = qkvb; ep.qscale = 0.17677669529663687f;
    gemm_fk2<<<dim3(3, 256), 512, 0, stream>>>(sbuf, qkvF + (size_t)i * 196608, 768, ep);

    attn_v3<<<1024, 256, 0, stream>>>(qkvb, biasb, i, sbuf);

    ep = EpiParams{};
    ep.bias = proj_b + i * 256; ep.of32 = x_cur; ep.resid = xin; ep.shift = shift;
    gemm_fk<2><<<dim3(2, 256), 512, 0, stream>>>(sbuf, projF + (size_t)i * 65536, 256, ep);

    fused_mlp<<<512, 512, 0, stream>>>(x_cur, ln2_g + i * 256, ln2_b + i * 256,
                                       W1f + (size_t)i * 262144, W2f + (size_t)i * 262144,
                                       fc1_b + i * 1024, fc2_b + i * 256,
                                       (i == 1) ? (float*)d_out : x_cur);
  }
}

// Round 7
// 404.132 us; speedup vs baseline: 1.0740x; 1.0470x over previous
//
#include <hip/hip_runtime.h>

typedef unsigned short u16;
typedef __attribute__((ext_vector_type(8))) short short8;
typedef __attribute__((ext_vector_type(4))) float f32x4;

#define GLDS16(gp, sp) __builtin_amdgcn_global_load_lds( \
    (const __attribute__((address_space(1))) void*)(gp),  \
    (__attribute__((address_space(3))) void*)(sp), 16, 0, 0)

__device__ __forceinline__ u16 f2bf(float f) {
  union { float f; unsigned u; } x; x.f = f;
  unsigned r = (x.u + 0x7fffu + ((x.u >> 16) & 1u)) >> 16;  // RNE
  return (u16)r;
}
__device__ __forceinline__ float bf2f(u16 v) {
  union { unsigned u; float f; } x; x.u = ((unsigned)v) << 16; return x.f;
}
__device__ __forceinline__ unsigned cvt_pk_bf16(float lo, float hi) {
  unsigned r;
  asm("v_cvt_pk_bf16_f32 %0, %1, %2" : "=v"(r) : "v"(lo), "v"(hi));
  return r;
}

// ------- generic weight -> bf16 MFMA B-fragment order --------------------
__global__ __launch_bounds__(256) void wswizB(const float* __restrict__ W,
                                              u16* __restrict__ Wf, int K, int N) {
  int tid = blockIdx.x * 256 + threadIdx.x;
  int Kt = K >> 5, Nt = N >> 4;
  int per = Nt * Kt * 64;
  if (tid >= 2 * per) return;
  int l = tid >= per;
  int rem = tid - l * per;
  int nb = rem / (Kt * 64);
  int rem2 = rem - nb * Kt * 64;
  int ks = rem2 >> 6, lane = rem2 & 63;
  int n = nb * 16 + (lane & 15);
  u16 o[8];
  #pragma unroll
  for (int e = 0; e < 8; ++e) {
    int k = ks * 32 + ((lane >> 4) << 3) + e;
    o[e] = f2bf(W[((size_t)l * K + k) * N + n]);
  }
  *(uint4*)(Wf + ((size_t)tid << 3)) = *(uint4*)o;
}

// ------- fc1 weights -> B-fragment order: W1f[l][hc(8)][ks(8)][ntile(8)][lane][8]
__global__ __launch_bounds__(256) void wswiz1(const float* __restrict__ W,
                                              u16* __restrict__ Wf) {
  int tid = blockIdx.x * 256 + threadIdx.x;  // [0, 65536)
  int lane = tid & 63, nt = (tid >> 6) & 7, ks = (tid >> 9) & 7,
      hc = (tid >> 12) & 7, l = tid >> 15;
  int n = hc * 128 + nt * 16 + (lane & 15);
  u16 o[8];
  #pragma unroll
  for (int e = 0; e < 8; ++e) {
    int k = ks * 32 + ((lane >> 4) << 3) + e;
    o[e] = f2bf(W[((size_t)l * 256 + k) * 1024 + n]);
  }
  *(uint4*)(Wf + ((size_t)tid << 3)) = *(uint4*)o;
}

// ------- fc2 weights -> B-fragment order: W2f[l][hc(8)][ks(4)][ntile(16)][lane][8]
__global__ __launch_bounds__(256) void wswiz2(const float* __restrict__ W,
                                              u16* __restrict__ Wf) {
  int tid = blockIdx.x * 256 + threadIdx.x;  // [0, 65536)
  int lane = tid & 63, nt = (tid >> 6) & 15, ks = (tid >> 10) & 3,
      hc = (tid >> 12) & 7, l = tid >> 15;
  int n = nt * 16 + (lane & 15);
  u16 o[8];
  #pragma unroll
  for (int e = 0; e < 8; ++e) {
    int k = hc * 128 + ks * 32 + ((lane >> 4) << 3) + e;
    o[e] = f2bf(W[((size_t)l * 1024 + k) * 256 + n]);
  }
  *(uint4*)(Wf + ((size_t)tid << 3)) = *(uint4*)o;
}

// ------- rel-pos bias gather, bf16, pre-swizzled to SWAPPED MFMA C-layout ---
// Swapped attn computes S^T = mfma(K,Q): C layout col=query(lane&15),
// row=key(quad*4+r). bias'[e]: query = mslot*16+(lane&15),
// key = nt*16 + ((lane>>4)<<2) + r.
__global__ __launch_bounds__(256) void bias_gb(const float* __restrict__ rpb,
                                               const int* __restrict__ rpi,
                                               u16* __restrict__ biasb) {
  int tid = blockIdx.x * 256 + threadIdx.x;  // [0, 2*65536)
  if (tid >= 131072) return;
  int l = tid >> 16, cid = tid & 65535;
  int lane = cid & 63, k = (cid >> 6) & 7, mslot = (cid >> 9) & 15, h = cid >> 13;
  u16 o[8];
  #pragma unroll
  for (int e = 0; e < 8; ++e) {
    int nt = 2 * k + (e >> 2), r = e & 3;
    int i = mslot * 16 + (lane & 15);              // query
    int j = nt * 16 + ((lane >> 4) << 2) + r;      // key
    int idx = rpi[i * 256 + j];
    o[e] = f2bf(rpb[((size_t)l * 961 + idx) * 8 + h]);
  }
  *(uint4*)(biasb + ((size_t)tid << 3)) = *(uint4*)o;
}

// ---------------- LN1 + shift + window partition -> bf16 wins ---------------
__global__ __launch_bounds__(256) void ln_part(const float* __restrict__ x,
                                               const float* __restrict__ g,
                                               const float* __restrict__ b,
                                               u16* __restrict__ out, int shift) {
  int wv = threadIdx.x >> 6, lane = threadIdx.x & 63;
  int wtok = blockIdx.x * 4 + wv;
  int w = wtok >> 8, t = wtok & 255;
  int bimg = w >> 4, wi = w & 15;
  int ph = (((wi >> 2) << 4) + (t >> 4) + shift) & 63;
  int pw = (((wi & 3) << 4) + (t & 15) + shift) & 63;
  const float4 v = *(const float4*)(x + ((size_t)((bimg * 64 + ph) * 64 + pw)) * 256 + lane * 4);
  float s = v.x + v.y + v.z + v.w;
  float sq = v.x * v.x + v.y * v.y + v.z * v.z + v.w * v.w;
  #pragma unroll
  for (int m = 1; m < 64; m <<= 1) { s += __shfl_xor(s, m, 64); sq += __shfl_xor(sq, m, 64); }
  float mean = s * (1.f / 256.f);
  float var = sq * (1.f / 256.f) - mean * mean;
  float rs = rsqrtf(var + 1e-5f);
  float4 gg = *(const float4*)(g + lane * 4);
  float4 bb = *(const float4*)(b + lane * 4);
  uint2 pk;
  pk.x = cvt_pk_bf16((v.x - mean) * rs * gg.x + bb.x,
                     (v.y - mean) * rs * gg.y + bb.y);
  pk.y = cvt_pk_bf16((v.z - mean) * rs * gg.z + bb.z,
                     (v.w - mean) * rs * gg.w + bb.w);
  *(uint2*)(out + (size_t)wtok * 256 + lane * 4) = pk;
}

struct EpiParams {
  const float* bias;
  u16* obf;
  float* of32;
  const float* resid;
  int shift;
  float qscale;
};

// ---------------- GEMM v2: 128x256 tile, full-K staged, A-read reuse x4 -----
__global__ __launch_bounds__(512, 2) void gemm_fk2(const u16* __restrict__ A,
                                                   const u16* __restrict__ Wf,
                                                   int N, EpiParams ep) {
  __shared__ u16 As[8][128][32];   // 64 KB
  int tid = threadIdx.x;
  int n0 = blockIdx.x * 256, m0 = blockIdx.y * 128;
  int wv = tid >> 6, lane = tid & 63, quad = lane >> 4, l15 = lane & 15;
  int wm = wv & 1, wn = wv >> 1;   // wn in 0..3

  #pragma unroll
  for (int i = 0; i < 8; ++i) {
    int c = i * 512 + tid;
    int kb = c >> 9, rc = c & 511;
    int row = rc >> 2, kc = (rc & 3) * 8;
    GLDS16(A + (size_t)(m0 + row) * 256 + kb * 32 + kc, &As[kb][row][kc]);
  }
  __syncthreads();

  f32x4 acc[4][4] = {};
  #pragma unroll
  for (int kb = 0; kb < 8; ++kb) {
    short8 bf[4];
    #pragma unroll
    for (int nt = 0; nt < 4; ++nt) {
      size_t ntile = (size_t)(blockIdx.x * 16 + wn * 4 + nt);
      bf[nt] = *(const short8*)(Wf + ((ntile * 8 + kb) * 64 + lane) * 8);
    }
    #pragma unroll
    for (int mt = 0; mt < 4; ++mt) {
      short8 af = *(const short8*)&As[kb][wm * 64 + mt * 16 + l15][quad * 8];
      #pragma unroll
      for (int nt = 0; nt < 4; ++nt)
        acc[mt][nt] = __builtin_amdgcn_mfma_f32_16x16x32_bf16(af, bf[nt], acc[mt][nt], 0, 0, 0);
    }
  }

  #pragma unroll
  for (int mt = 0; mt < 4; ++mt) {
    #pragma unroll
    for (int nt = 0; nt < 4; ++nt) {
      #pragma unroll
      for (int r = 0; r < 4; ++r) {
        int grow = m0 + wm * 64 + mt * 16 + quad * 4 + r;
        int gcol = n0 + wn * 64 + nt * 16 + l15;
        float v = acc[mt][nt][r] + ep.bias[gcol];
        if (gcol < 256) v *= ep.qscale;
        ep.obf[(size_t)grow * N + gcol] = f2bf(v);
      }
    }
  }
}

// ---------------- GEMM, full-K staged (round-7, used for proj) --------------
template <int EPI>
__global__ __launch_bounds__(512, 2) void gemm_fk(const u16* __restrict__ A,
                                                  const u16* __restrict__ Wf,
                                                  int N, EpiParams ep) {
  __shared__ u16 As[8][128][32];   // 64 KB
  int tid = threadIdx.x;
  int n0 = blockIdx.x * 128, m0 = blockIdx.y * 128;
  int wv = tid >> 6, lane = tid & 63, quad = lane >> 4, l15 = lane & 15;
  int wm = wv & 1, wn = wv >> 1;

  #pragma unroll
  for (int i = 0; i < 8; ++i) {
    int c = i * 512 + tid;
    int kb = c >> 9, rc = c & 511;
    int row = rc >> 2, kc = (rc & 3) * 8;
    GLDS16(A + (size_t)(m0 + row) * 256 + kb * 32 + kc, &As[kb][row][kc]);
  }
  __syncthreads();

  f32x4 acc[4][2] = {};
  #pragma unroll
  for (int kb = 0; kb < 8; ++kb) {
    short8 bf[2];
    #pragma unroll
    for (int nt = 0; nt < 2; ++nt) {
      size_t ntile = (size_t)(blockIdx.x * 8 + wn * 2 + nt);
      bf[nt] = *(const short8*)(Wf + ((ntile * 8 + kb) * 64 + lane) * 8);
    }
    #pragma unroll
    for (int mt = 0; mt < 4; ++mt) {
      short8 af = *(const short8*)&As[kb][wm * 64 + mt * 16 + l15][quad * 8];
      #pragma unroll
      for (int nt = 0; nt < 2; ++nt)
        acc[mt][nt] = __builtin_amdgcn_mfma_f32_16x16x32_bf16(af, bf[nt], acc[mt][nt], 0, 0, 0);
    }
  }

  #pragma unroll
  for (int mt = 0; mt < 4; ++mt) {
    #pragma unroll
    for (int nt = 0; nt < 2; ++nt) {
      #pragma unroll
      for (int r = 0; r < 4; ++r) {
        int grow = m0 + wm * 64 + mt * 16 + quad * 4 + r;
        int gcol = n0 + wn * 32 + nt * 16 + l15;
        float v = acc[mt][nt][r] + ep.bias[gcol];
        if constexpr (EPI == 0) {
          if (gcol < 256) v *= ep.qscale;
          ep.obf[(size_t)grow * N + gcol] = f2bf(v);
        } else {
          int w_ = grow >> 8, t = grow & 255, wi = w_ & 15;
          int ph = (((wi >> 2) << 4) + (t >> 4) + ep.shift) & 63;
          int pw = (((wi & 3) << 4) + (t & 15) + ep.shift) & 63;
          size_t pix = (size_t)(((w_ >> 4) * 64 + ph) * 64 + pw);
          ep.of32[pix * 256 + gcol] = ep.resid[pix * 256 + gcol] + v;
        }
      }
    }
  }
}

// ---------------- fused MLP v9 (kept: 56.0us measured, best) ----------------
__global__ __launch_bounds__(512, 4) void fused_mlp(const float* __restrict__ xin,
                                                    const float* __restrict__ g,
                                                    const float* __restrict__ b,
                                                    const u16* __restrict__ W1f,
                                                    const u16* __restrict__ W2f,
                                                    const float* __restrict__ b1p,
                                                    const float* __restrict__ b2p,
                                                    float* __restrict__ out) {
  __shared__ u16 Zs[64 * 264];
  __shared__ u16 Hs[2][64 * 136];
  int tid = threadIdx.x, wv = tid >> 6, lane = tid & 63;
  int quad = lane >> 4, l15 = lane & 15;
  int m0 = blockIdx.x * 64;

  float4 gg = *(const float4*)(g + lane * 4);
  float4 bb = *(const float4*)(b + lane * 4);
  #pragma unroll
  for (int rr = 0; rr < 8; ++rr) {
    int row = wv * 8 + rr;
    const float4 v = *(const float4*)(xin + (size_t)(m0 + row) * 256 + lane * 4);
    float s = v.x + v.y + v.z + v.w;
    float sq = v.x * v.x + v.y * v.y + v.z * v.z + v.w * v.w;
    #pragma unroll
    for (int m = 1; m < 64; m <<= 1) { s += __shfl_xor(s, m, 64); sq += __shfl_xor(sq, m, 64); }
    float mean = s * (1.f / 256.f);
    float var = sq * (1.f / 256.f) - mean * mean;
    float rs = rsqrtf(var + 1e-5f);
    u16 o0 = f2bf((v.x - mean) * rs * gg.x + bb.x);
    u16 o1 = f2bf((v.y - mean) * rs * gg.y + bb.y);
    u16 o2 = f2bf((v.z - mean) * rs * gg.z + bb.z);
    u16 o3 = f2bf((v.w - mean) * rs * gg.w + bb.w);
    uint2 pk; pk.x = (unsigned)o0 | ((unsigned)o1 << 16); pk.y = (unsigned)o2 | ((unsigned)o3 << 16);
    *(uint2*)&Zs[row * 264 + lane * 4] = pk;
  }
  __syncthreads();

  f32x4 acc2[4][2];
  #pragma unroll
  for (int nt = 0; nt < 2; ++nt) {
    float b2 = b2p[wv * 32 + nt * 16 + l15];
    #pragma unroll
    for (int mt = 0; mt < 4; ++mt)
      #pragma unroll
      for (int r = 0; r < 4; ++r) acc2[mt][nt][r] = b2;
  }

  for (int hp = 0; hp < 4; ++hp) {
    int hcA = 2 * hp, hcB = 2 * hp + 1;
    f32x4 acc1a[4], acc1b[4];
    {
      float b1a = b1p[hcA * 128 + wv * 16 + l15];
      float b1b = b1p[hcB * 128 + wv * 16 + l15];
      #pragma unroll
      for (int mt = 0; mt < 4; ++mt)
        #pragma unroll
        for (int r = 0; r < 4; ++r) { acc1a[mt][r] = b1a; acc1b[mt][r] = b1b; }
    }
    #pragma unroll
    for (int ks = 0; ks < 8; ++ks) {
      short8 bfa = *(const short8*)(W1f + ((((size_t)hcA * 8 + ks) * 8 + wv) * 64 + lane) * 8);
      short8 bfb = *(const short8*)(W1f + ((((size_t)hcB * 8 + ks) * 8 + wv) * 64 + lane) * 8);
      __builtin_amdgcn_s_setprio(1);
      #pragma unroll
      for (int mt = 0; mt < 4; ++mt) {
        short8 af = *(const short8*)&Zs[(mt * 16 + l15) * 264 + ks * 32 + quad * 8];
        acc1a[mt] = __builtin_amdgcn_mfma_f32_16x16x32_bf16(af, bfa, acc1a[mt], 0, 0, 0);
        acc1b[mt] = __builtin_amdgcn_mfma_f32_16x16x32_bf16(af, bfb, acc1b[mt], 0, 0, 0);
      }
      __builtin_amdgcn_s_setprio(0);
    }
    #pragma unroll
    for (int mt = 0; mt < 4; ++mt)
      #pragma unroll
      for (int r = 0; r < 4; ++r) {
        float va = acc1a[mt][r];
        float ia = va * (1.f + 0.044715f * va * va);
        float ea = __expf(-1.5957691216057308f * ia);
        Hs[0][(mt * 16 + quad * 4 + r) * 136 + wv * 16 + l15] =
            f2bf(va * __builtin_amdgcn_rcpf(1.f + ea));
        float vb = acc1b[mt][r];
        float ib = vb * (1.f + 0.044715f * vb * vb);
        float eb = __expf(-1.5957691216057308f * ib);
        Hs[1][(mt * 16 + quad * 4 + r) * 136 + wv * 16 + l15] =
            f2bf(vb * __builtin_amdgcn_rcpf(1.f + eb));
      }
    __syncthreads();
    #pragma unroll
    for (int buf = 0; buf < 2; ++buf) {
      int hc = 2 * hp + buf;
      #pragma unroll
      for (int ks = 0; ks < 4; ++ks) {
        short8 bf2[2];
        #pragma unroll
        for (int nt = 0; nt < 2; ++nt)
          bf2[nt] = *(const short8*)(W2f + ((((size_t)hc * 4 + ks) * 16 + wv * 2 + nt) * 64 + lane) * 8);
        __builtin_amdgcn_s_setprio(1);
        #pragma unroll
        for (int mt = 0; mt < 4; ++mt) {
          short8 af2 = *(const short8*)&Hs[buf][(mt * 16 + l15) * 136 + ks * 32 + quad * 8];
          #pragma unroll
          for (int nt = 0; nt < 2; ++nt)
            acc2[mt][nt] = __builtin_amdgcn_mfma_f32_16x16x32_bf16(af2, bf2[nt], acc2[mt][nt], 0, 0, 0);
        }
        __builtin_amdgcn_s_setprio(0);
      }
    }
    __syncthreads();
  }

  #pragma unroll
  for (int mt = 0; mt < 4; ++mt)
    #pragma unroll
    for (int nt = 0; nt < 2; ++nt)
      #pragma unroll
      for (int r = 0; r < 4; ++r) {
        size_t idx = (size_t)(m0 + mt * 16 + quad * 4 + r) * 256 + wv * 32 + nt * 16 + l15;
        out[idx] = xin[idx] + acc2[mt][nt][r];
      }
}

// ---------------- fused window attention v4: operand-swapped QK^T -----------
// S^T = mfma(K_frag, Q_frag): lane (quad,l15) holds S[key=nt*16+quad*4+r]
// [query=mslot*16+l15] -> per-thread softmax over its 64 keys (one query),
// only 2 shuffles (xor16/32) per reduction; P normalized in-register, packed
// with cvt_pk, 2 ds_write_b64 per kk (was 8 scalar u16 + 4-way conflicts).
// Q/K fragment loads and PV loop identical to v3.
__global__ __launch_bounds__(256, 4) void attn_v3(const u16* __restrict__ qkv,
                                                  const u16* __restrict__ biasb,
                                                  int layer, u16* __restrict__ aout) {
  __shared__ u16 Klds[256 * 32];
  __shared__ u16 Vt[32 * 264];
  __shared__ u16 Plds[4][16 * 40];
  int bid = blockIdx.x;
  int lw = ((bid & 7) << 7) | (bid >> 3);   // XCD swizzle
  int w = lw >> 3, h = lw & 7;
  int tid = threadIdx.x;

  {
    const uint4* kp = (const uint4*)(qkv + ((size_t)(w * 256 + tid)) * 768 + 256 + h * 32);
    uint4* kd = (uint4*)&Klds[tid * 32];
    kd[0] = kp[0]; kd[1] = kp[1]; kd[2] = kp[2]; kd[3] = kp[3];
    const uint4* vp = (const uint4*)(qkv + ((size_t)(w * 256 + tid)) * 768 + 512 + h * 32);
    u16 vt[32];
    *(uint4*)&vt[0]  = vp[0];
    *(uint4*)&vt[8]  = vp[1];
    *(uint4*)&vt[16] = vp[2];
    *(uint4*)&vt[24] = vp[3];
    #pragma unroll
    for (int d = 0; d < 32; ++d) Vt[d * 264 + tid] = vt[d];
  }
  __syncthreads();

  int wv = tid >> 6, lane = tid & 63, quad = lane >> 4, l15 = lane & 15;
  int wi = w & 15, wr = wi >> 2, wc = wi & 3;
  const bool masked = (layer != 0) && (wr == 3 || wc == 3);
  // key-side column class (fixed per thread): key tw = quad*4+r, all r share quad<2
  int ckey_w = (wc == 3) ? (quad < 2 ? 1 : 2) : 0;
  // query-side column class: query tw = l15
  int cq_w = (wc == 3) ? (l15 < 8 ? 1 : 2) : 0;

  #pragma unroll
  for (int mt = 0; mt < 4; ++mt) {
    int mslot = wv * 4 + mt;
    int m0 = mslot * 16;
    short8 aq = *(const short8*)(qkv + ((size_t)(w * 256 + m0 + l15)) * 768 + h * 32 + quad * 8);
    const u16* bmt = biasb + ((size_t)layer << 19) + ((size_t)h << 16) + (size_t)mslot * 4096;
    f32x4 c[16];
    #pragma unroll
    for (int k = 0; k < 8; ++k) {
      short8 bv = *(const short8*)(bmt + k * 512 + lane * 8);
      #pragma unroll
      for (int r = 0; r < 4; ++r) {
        c[2 * k][r]     = bf2f((u16)bv[r]);
        c[2 * k + 1][r] = bf2f((u16)bv[4 + r]);
      }
    }
    // S^T: A = K tile (rows=keys), B = Q tile (cols=queries)
    #pragma unroll
    for (int nt = 0; nt < 16; ++nt) {
      short8 bk = *(const short8*)&Klds[(nt * 16 + l15) * 32 + quad * 8];
      c[nt] = __builtin_amdgcn_mfma_f32_16x16x32_bf16(bk, aq, c[nt], 0, 0, 0);
    }
    if (masked) {
      int regi = ((wr == 3) ? (mslot < 8 ? 1 : 2) : 0) * 3 + cq_w;  // query class
      #pragma unroll
      for (int nt = 0; nt < 16; ++nt) {
        int regj = ((wr == 3) ? (nt < 8 ? 1 : 2) : 0) * 3 + ckey_w; // key class
        float madd = (regi != regj) ? -100.f : 0.f;
        #pragma unroll
        for (int r = 0; r < 4; ++r) c[nt][r] += madd;
      }
    }
    // per-thread softmax over 64 keys of query l15 (+2 shuffles across quads)
    float pm = -1e30f;
    #pragma unroll
    for (int nt = 0; nt < 16; ++nt)
      #pragma unroll
      for (int r = 0; r < 4; ++r) pm = fmaxf(pm, c[nt][r]);
    pm = fmaxf(pm, __shfl_xor(pm, 16, 64));
    pm = fmaxf(pm, __shfl_xor(pm, 32, 64));
    float ps = 0.f;
    #pragma unroll
    for (int nt = 0; nt < 16; ++nt)
      #pragma unroll
      for (int r = 0; r < 4; ++r) {
        float e = __expf(c[nt][r] - pm);
        c[nt][r] = e;
        ps += e;
      }
    ps += __shfl_xor(ps, 16, 64);
    ps += __shfl_xor(ps, 32, 64);
    float inv = 1.f / ps;

    // PV: normalize + pack P^T tile per kk, 2 b64 writes, b128 A-frag read
    f32x4 o0 = {0.f, 0.f, 0.f, 0.f}, o1 = {0.f, 0.f, 0.f, 0.f};
    #pragma unroll
    for (int kk = 0; kk < 8; ++kk) {
      uint2 wA, wB;
      wA.x = cvt_pk_bf16(c[2 * kk][0] * inv, c[2 * kk][1] * inv);
      wA.y = cvt_pk_bf16(c[2 * kk][2] * inv, c[2 * kk][3] * inv);
      wB.x = cvt_pk_bf16(c[2 * kk + 1][0] * inv, c[2 * kk + 1][1] * inv);
      wB.y = cvt_pk_bf16(c[2 * kk + 1][2] * inv, c[2 * kk + 1][3] * inv);
      *(uint2*)&Plds[wv][l15 * 40 + quad * 4] = wA;
      *(uint2*)&Plds[wv][l15 * 40 + 16 + quad * 4] = wB;
      short8 ap = *(const short8*)&Plds[wv][l15 * 40 + quad * 8];
      short8 bv0 = *(const short8*)&Vt[l15 * 264 + kk * 32 + quad * 8];
      short8 bv1 = *(const short8*)&Vt[(16 + l15) * 264 + kk * 32 + quad * 8];
      o0 = __builtin_amdgcn_mfma_f32_16x16x32_bf16(ap, bv0, o0, 0, 0, 0);
      o1 = __builtin_amdgcn_mfma_f32_16x16x32_bf16(ap, bv1, o1, 0, 0, 0);
    }
    #pragma unroll
    for (int r = 0; r < 4; ++r) {
      size_t row = (size_t)(w * 256 + m0 + quad * 4 + r);
      aout[row * 256 + h * 32 + l15] = f2bf(o0[r]);
      aout[row * 256 + h * 32 + 16 + l15] = f2bf(o1[r]);
    }
  }
}

// ----------------------------------------------------------------------------
extern "C" void kernel_launch(void* const* d_in, const int* in_sizes, int n_in,
                              void* d_out, int out_size, void* d_ws, size_t ws_size,
                              hipStream_t stream) {
  const float* x      = (const float*)d_in[0];
  const float* ln1_g  = (const float*)d_in[1];
  const float* ln1_b  = (const float*)d_in[2];
  const float* qkv_w  = (const float*)d_in[3];
  const float* qkv_b  = (const float*)d_in[4];
  const float* rpb    = (const float*)d_in[5];
  const float* proj_w = (const float*)d_in[6];
  const float* proj_b = (const float*)d_in[7];
  const float* ln2_g  = (const float*)d_in[8];
  const float* ln2_b  = (const float*)d_in[9];
  const float* fc1_w  = (const float*)d_in[10];
  const float* fc1_b  = (const float*)d_in[11];
  const float* fc2_w  = (const float*)d_in[12];
  const float* fc2_b  = (const float*)d_in[13];
  const int*   rpi    = (const int*)d_in[15];

  char* ws = (char*)d_ws;
  size_t off = 0;
  auto alloc = [&](size_t bytes) { void* p = ws + off; off += (bytes + 255) & ~(size_t)255; return p; };
  float* x_cur   = (float*)alloc((size_t)32768 * 256 * 4);   // residual stream
  u16* sbuf      = (u16*)alloc((size_t)32768 * 256 * 2);     // wins -> attn_out
  u16* qkvb      = (u16*)alloc((size_t)32768 * 768 * 2);
  u16* biasb     = (u16*)alloc((size_t)2 * 8 * 65536 * 2);   // pre-swizzled bf16 bias
  u16* qkvF      = (u16*)alloc((size_t)2 * 196608 * 2);      // qkv B-fragments
  u16* projF     = (u16*)alloc((size_t)2 * 65536 * 2);       // proj B-fragments
  u16* W1f       = (u16*)alloc((size_t)2 * 262144 * 2);      // fc1 B-fragments
  u16* W2f       = (u16*)alloc((size_t)2 * 262144 * 2);      // fc2 B-fragments

  // prep
  wswizB<<<192, 256, 0, stream>>>(qkv_w, qkvF, 256, 768);
  wswizB<<<64, 256, 0, stream>>>(proj_w, projF, 256, 256);
  wswiz1<<<256, 256, 0, stream>>>(fc1_w, W1f);
  wswiz2<<<256, 256, 0, stream>>>(fc2_w, W2f);
  bias_gb<<<512, 256, 0, stream>>>(rpb, rpi, biasb);

  for (int i = 0; i < 2; ++i) {
    int shift = i ? 8 : 0;
    const float* xin = i ? x_cur : x;

    ln_part<<<8192, 256, 0, stream>>>(xin, ln1_g + i * 256, ln1_b + i * 256, sbuf, shift);

    EpiParams ep{};
    ep.bias = qkv_b + i * 768; ep.obf = qkvb; ep.qscale = 0.17677669529663687f;
    gemm_fk2<<<dim3(3, 256), 512, 0, stream>>>(sbuf, qkvF + (size_t)i * 196608, 768, ep);

    attn_v3<<<1024, 256, 0, stream>>>(qkvb, biasb, i, sbuf);

    ep = EpiParams{};
    ep.bias = proj_b + i * 256; ep.of32 = x_cur; ep.resid = xin; ep.shift = shift;
    gemm_fk<2><<<dim3(2, 256), 512, 0, stream>>>(sbuf, projF + (size_t)i * 65536, 256, ep);

    fused_mlp<<<512, 512, 0, stream>>>(x_cur, ln2_g + i * 256, ln2_b + i * 256,
                                       W1f + (size_t)i * 262144, W2f + (size_t)i * 262144,
                                       fc1_b + i * 1024, fc2_b + i * 256,
                                       (i == 1) ? (float*)d_out : x_cur);
  }
}

// Round 8
// 392.138 us; speedup vs baseline: 1.1069x; 1.0306x over previous
//
#include <hip/hip_runtime.h>

typedef unsigned short u16;
typedef __attribute__((ext_vector_type(8))) short short8;
typedef __attribute__((ext_vector_type(4))) float f32x4;

#define GLDS16(gp, sp) __builtin_amdgcn_global_load_lds( \
    (const __attribute__((address_space(1))) void*)(gp),  \
    (__attribute__((address_space(3))) void*)(sp), 16, 0, 0)

__device__ __forceinline__ u16 f2bf(float f) {
  union { float f; unsigned u; } x; x.f = f;
  unsigned r = (x.u + 0x7fffu + ((x.u >> 16) & 1u)) >> 16;  // RNE
  return (u16)r;
}
__device__ __forceinline__ float bf2f(u16 v) {
  union { unsigned u; float f; } x; x.u = ((unsigned)v) << 16; return x.f;
}
__device__ __forceinline__ unsigned cvt_pk_bf16(float lo, float hi) {
  unsigned r;
  asm("v_cvt_pk_bf16_f32 %0, %1, %2" : "=v"(r) : "v"(lo), "v"(hi));
  return r;
}

// ------- generic weight -> bf16 MFMA B-fragment order --------------------
__global__ __launch_bounds__(256) void wswizB(const float* __restrict__ W,
                                              u16* __restrict__ Wf, int K, int N) {
  int tid = blockIdx.x * 256 + threadIdx.x;
  int Kt = K >> 5, Nt = N >> 4;
  int per = Nt * Kt * 64;
  if (tid >= 2 * per) return;
  int l = tid >= per;
  int rem = tid - l * per;
  int nb = rem / (Kt * 64);
  int rem2 = rem - nb * Kt * 64;
  int ks = rem2 >> 6, lane = rem2 & 63;
  int n = nb * 16 + (lane & 15);
  u16 o[8];
  #pragma unroll
  for (int e = 0; e < 8; ++e) {
    int k = ks * 32 + ((lane >> 4) << 3) + e;
    o[e] = f2bf(W[((size_t)l * K + k) * N + n]);
  }
  *(uint4*)(Wf + ((size_t)tid << 3)) = *(uint4*)o;
}

// ------- fc1 weights -> B-fragment order: W1f[l][hc(8)][ks(8)][ntile(8)][lane][8]
__global__ __launch_bounds__(256) void wswiz1(const float* __restrict__ W,
                                              u16* __restrict__ Wf) {
  int tid = blockIdx.x * 256 + threadIdx.x;  // [0, 65536)
  int lane = tid & 63, nt = (tid >> 6) & 7, ks = (tid >> 9) & 7,
      hc = (tid >> 12) & 7, l = tid >> 15;
  int n = hc * 128 + nt * 16 + (lane & 15);
  u16 o[8];
  #pragma unroll
  for (int e = 0; e < 8; ++e) {
    int k = ks * 32 + ((lane >> 4) << 3) + e;
    o[e] = f2bf(W[((size_t)l * 256 + k) * 1024 + n]);
  }
  *(uint4*)(Wf + ((size_t)tid << 3)) = *(uint4*)o;
}

// ------- fc2 weights -> B-fragment order: W2f[l][hc(8)][ks(4)][ntile(16)][lane][8]
__global__ __launch_bounds__(256) void wswiz2(const float* __restrict__ W,
                                              u16* __restrict__ Wf) {
  int tid = blockIdx.x * 256 + threadIdx.x;  // [0, 65536)
  int lane = tid & 63, nt = (tid >> 6) & 15, ks = (tid >> 10) & 3,
      hc = (tid >> 12) & 7, l = tid >> 15;
  int n = nt * 16 + (lane & 15);
  u16 o[8];
  #pragma unroll
  for (int e = 0; e < 8; ++e) {
    int k = hc * 128 + ks * 32 + ((lane >> 4) << 3) + e;
    o[e] = f2bf(W[((size_t)l * 1024 + k) * 256 + n]);
  }
  *(uint4*)(Wf + ((size_t)tid << 3)) = *(uint4*)o;
}

// ------- rel-pos bias gather, bf16, pre-swizzled to SWAPPED MFMA C-layout ---
__global__ __launch_bounds__(256) void bias_gb(const float* __restrict__ rpb,
                                               const int* __restrict__ rpi,
                                               u16* __restrict__ biasb) {
  int tid = blockIdx.x * 256 + threadIdx.x;  // [0, 2*65536)
  if (tid >= 131072) return;
  int l = tid >> 16, cid = tid & 65535;
  int lane = cid & 63, k = (cid >> 6) & 7, mslot = (cid >> 9) & 15, h = cid >> 13;
  u16 o[8];
  #pragma unroll
  for (int e = 0; e < 8; ++e) {
    int nt = 2 * k + (e >> 2), r = e & 3;
    int i = mslot * 16 + (lane & 15);              // query
    int j = nt * 16 + ((lane >> 4) << 2) + r;      // key
    int idx = rpi[i * 256 + j];
    o[e] = f2bf(rpb[((size_t)l * 961 + idx) * 8 + h]);
  }
  *(uint4*)(biasb + ((size_t)tid << 3)) = *(uint4*)o;
}

struct EpiParams {
  const float* bias;
  u16* obf;
  float* of32;
  const float* resid;
  int shift;
  float qscale;
};

// ---------------- fused LN1 + window partition + qkv GEMM -------------------
// Replaces ln_part + gemm_fk2: LN computed in-kernel (3x redundant across the
// N-split blocks; x is L3-resident so re-reads are cache hits) and written
// straight into the As fragment layout via packed ds_write_b64. Kills one
// dispatch/layer and the 16MB sbuf HBM round-trip. MFMA loop and epilogue are
// byte-identical to the proven gemm_fk2.
__global__ __launch_bounds__(512, 2) void ln_qkv(const float* __restrict__ x,
                                                 const float* __restrict__ g,
                                                 const float* __restrict__ b,
                                                 const u16* __restrict__ Wf,
                                                 int N, EpiParams ep) {
  __shared__ u16 As[8][128][32];   // 64 KB
  int tid = threadIdx.x;
  int n0 = blockIdx.x * 256, m0 = blockIdx.y * 128;
  int wv = tid >> 6, lane = tid & 63, quad = lane >> 4, l15 = lane & 15;
  int wm = wv & 1, wn = wv >> 1;   // wn in 0..3

  // ---- LN staging: 16 rows per wave, thread owns 4 channels (lane*4..+3)
  {
    float4 gg = *(const float4*)(g + lane * 4);
    float4 bb = *(const float4*)(b + lane * 4);
    #pragma unroll
    for (int rr = 0; rr < 16; ++rr) {
      int row = wv * 16 + rr;
      int wtok = m0 + row;
      int w = wtok >> 8, t = wtok & 255;
      int bimg = w >> 4, wi = w & 15;
      int ph = (((wi >> 2) << 4) + (t >> 4) + ep.shift) & 63;
      int pw = (((wi & 3) << 4) + (t & 15) + ep.shift) & 63;
      const float4 v = *(const float4*)(x + ((size_t)((bimg * 64 + ph) * 64 + pw)) * 256 + lane * 4);
      float s = v.x + v.y + v.z + v.w;
      float sq = v.x * v.x + v.y * v.y + v.z * v.z + v.w * v.w;
      #pragma unroll
      for (int m = 1; m < 64; m <<= 1) { s += __shfl_xor(s, m, 64); sq += __shfl_xor(sq, m, 64); }
      float mean = s * (1.f / 256.f);
      float rs = rsqrtf(sq * (1.f / 256.f) - mean * mean + 1e-5f);
      uint2 pk;
      pk.x = cvt_pk_bf16((v.x - mean) * rs * gg.x + bb.x,
                         (v.y - mean) * rs * gg.y + bb.y);
      pk.y = cvt_pk_bf16((v.z - mean) * rs * gg.z + bb.z,
                         (v.w - mean) * rs * gg.w + bb.w);
      // channels lane*4..lane*4+3 -> As[kb=lane>>3][row][kc=(lane&7)*4]
      *(uint2*)&As[lane >> 3][row][(lane & 7) * 4] = pk;
    }
  }
  __syncthreads();

  f32x4 acc[4][4] = {};
  #pragma unroll
  for (int kb = 0; kb < 8; ++kb) {
    short8 bf[4];
    #pragma unroll
    for (int nt = 0; nt < 4; ++nt) {
      size_t ntile = (size_t)(blockIdx.x * 16 + wn * 4 + nt);
      bf[nt] = *(const short8*)(Wf + ((ntile * 8 + kb) * 64 + lane) * 8);
    }
    #pragma unroll
    for (int mt = 0; mt < 4; ++mt) {
      short8 af = *(const short8*)&As[kb][wm * 64 + mt * 16 + l15][quad * 8];
      #pragma unroll
      for (int nt = 0; nt < 4; ++nt)
        acc[mt][nt] = __builtin_amdgcn_mfma_f32_16x16x32_bf16(af, bf[nt], acc[mt][nt], 0, 0, 0);
    }
  }

  #pragma unroll
  for (int mt = 0; mt < 4; ++mt) {
    #pragma unroll
    for (int nt = 0; nt < 4; ++nt) {
      #pragma unroll
      for (int r = 0; r < 4; ++r) {
        int grow = m0 + wm * 64 + mt * 16 + quad * 4 + r;
        int gcol = n0 + wn * 64 + nt * 16 + l15;
        float v = acc[mt][nt][r] + ep.bias[gcol];
        if (gcol < 256) v *= ep.qscale;
        ep.obf[(size_t)grow * N + gcol] = f2bf(v);
      }
    }
  }
}

// ---------------- GEMM, full-K staged (used for proj) -----------------------
template <int EPI>
__global__ __launch_bounds__(512, 2) void gemm_fk(const u16* __restrict__ A,
                                                  const u16* __restrict__ Wf,
                                                  int N, EpiParams ep) {
  __shared__ u16 As[8][128][32];   // 64 KB
  int tid = threadIdx.x;
  int n0 = blockIdx.x * 128, m0 = blockIdx.y * 128;
  int wv = tid >> 6, lane = tid & 63, quad = lane >> 4, l15 = lane & 15;
  int wm = wv & 1, wn = wv >> 1;

  #pragma unroll
  for (int i = 0; i < 8; ++i) {
    int c = i * 512 + tid;
    int kb = c >> 9, rc = c & 511;
    int row = rc >> 2, kc = (rc & 3) * 8;
    GLDS16(A + (size_t)(m0 + row) * 256 + kb * 32 + kc, &As[kb][row][kc]);
  }
  __syncthreads();

  f32x4 acc[4][2] = {};
  #pragma unroll
  for (int kb = 0; kb < 8; ++kb) {
    short8 bf[2];
    #pragma unroll
    for (int nt = 0; nt < 2; ++nt) {
      size_t ntile = (size_t)(blockIdx.x * 8 + wn * 2 + nt);
      bf[nt] = *(const short8*)(Wf + ((ntile * 8 + kb) * 64 + lane) * 8);
    }
    #pragma unroll
    for (int mt = 0; mt < 4; ++mt) {
      short8 af = *(const short8*)&As[kb][wm * 64 + mt * 16 + l15][quad * 8];
      #pragma unroll
      for (int nt = 0; nt < 2; ++nt)
        acc[mt][nt] = __builtin_amdgcn_mfma_f32_16x16x32_bf16(af, bf[nt], acc[mt][nt], 0, 0, 0);
    }
  }

  #pragma unroll
  for (int mt = 0; mt < 4; ++mt) {
    #pragma unroll
    for (int nt = 0; nt < 2; ++nt) {
      #pragma unroll
      for (int r = 0; r < 4; ++r) {
        int grow = m0 + wm * 64 + mt * 16 + quad * 4 + r;
        int gcol = n0 + wn * 32 + nt * 16 + l15;
        float v = acc[mt][nt][r] + ep.bias[gcol];
        if constexpr (EPI == 0) {
          if (gcol < 256) v *= ep.qscale;
          ep.obf[(size_t)grow * N + gcol] = f2bf(v);
        } else {
          int w_ = grow >> 8, t = grow & 255, wi = w_ & 15;
          int ph = (((wi >> 2) << 4) + (t >> 4) + ep.shift) & 63;
          int pw = (((wi & 3) << 4) + (t & 15) + ep.shift) & 63;
          size_t pix = (size_t)(((w_ >> 4) * 64 + ph) * 64 + pw);
          ep.of32[pix * 256 + gcol] = ep.resid[pix * 256 + gcol] + v;
        }
      }
    }
  }
}

// ---------------- fused MLP v9 (kept: 56.0us measured, best) ----------------
__global__ __launch_bounds__(512, 4) void fused_mlp(const float* __restrict__ xin,
                                                    const float* __restrict__ g,
                                                    const float* __restrict__ b,
                                                    const u16* __restrict__ W1f,
                                                    const u16* __restrict__ W2f,
                                                    const float* __restrict__ b1p,
                                                    const float* __restrict__ b2p,
                                                    float* __restrict__ out) {
  __shared__ u16 Zs[64 * 264];
  __shared__ u16 Hs[2][64 * 136];
  int tid = threadIdx.x, wv = tid >> 6, lane = tid & 63;
  int quad = lane >> 4, l15 = lane & 15;
  int m0 = blockIdx.x * 64;

  float4 gg = *(const float4*)(g + lane * 4);
  float4 bb = *(const float4*)(b + lane * 4);
  #pragma unroll
  for (int rr = 0; rr < 8; ++rr) {
    int row = wv * 8 + rr;
    const float4 v = *(const float4*)(xin + (size_t)(m0 + row) * 256 + lane * 4);
    float s = v.x + v.y + v.z + v.w;
    float sq = v.x * v.x + v.y * v.y + v.z * v.z + v.w * v.w;
    #pragma unroll
    for (int m = 1; m < 64; m <<= 1) { s += __shfl_xor(s, m, 64); sq += __shfl_xor(sq, m, 64); }
    float mean = s * (1.f / 256.f);
    float var = sq * (1.f / 256.f) - mean * mean;
    float rs = rsqrtf(var + 1e-5f);
    u16 o0 = f2bf((v.x - mean) * rs * gg.x + bb.x);
    u16 o1 = f2bf((v.y - mean) * rs * gg.y + bb.y);
    u16 o2 = f2bf((v.z - mean) * rs * gg.z + bb.z);
    u16 o3 = f2bf((v.w - mean) * rs * gg.w + bb.w);
    uint2 pk; pk.x = (unsigned)o0 | ((unsigned)o1 << 16); pk.y = (unsigned)o2 | ((unsigned)o3 << 16);
    *(uint2*)&Zs[row * 264 + lane * 4] = pk;
  }
  __syncthreads();

  f32x4 acc2[4][2];
  #pragma unroll
  for (int nt = 0; nt < 2; ++nt) {
    float b2 = b2p[wv * 32 + nt * 16 + l15];
    #pragma unroll
    for (int mt = 0; mt < 4; ++mt)
      #pragma unroll
      for (int r = 0; r < 4; ++r) acc2[mt][nt][r] = b2;
  }

  for (int hp = 0; hp < 4; ++hp) {
    int hcA = 2 * hp, hcB = 2 * hp + 1;
    f32x4 acc1a[4], acc1b[4];
    {
      float b1a = b1p[hcA * 128 + wv * 16 + l15];
      float b1b = b1p[hcB * 128 + wv * 16 + l15];
      #pragma unroll
      for (int mt = 0; mt < 4; ++mt)
        #pragma unroll
        for (int r = 0; r < 4; ++r) { acc1a[mt][r] = b1a; acc1b[mt][r] = b1b; }
    }
    #pragma unroll
    for (int ks = 0; ks < 8; ++ks) {
      short8 bfa = *(const short8*)(W1f + ((((size_t)hcA * 8 + ks) * 8 + wv) * 64 + lane) * 8);
      short8 bfb = *(const short8*)(W1f + ((((size_t)hcB * 8 + ks) * 8 + wv) * 64 + lane) * 8);
      __builtin_amdgcn_s_setprio(1);
      #pragma unroll
      for (int mt = 0; mt < 4; ++mt) {
        short8 af = *(const short8*)&Zs[(mt * 16 + l15) * 264 + ks * 32 + quad * 8];
        acc1a[mt] = __builtin_amdgcn_mfma_f32_16x16x32_bf16(af, bfa, acc1a[mt], 0, 0, 0);
        acc1b[mt] = __builtin_amdgcn_mfma_f32_16x16x32_bf16(af, bfb, acc1b[mt], 0, 0, 0);
      }
      __builtin_amdgcn_s_setprio(0);
    }
    #pragma unroll
    for (int mt = 0; mt < 4; ++mt)
      #pragma unroll
      for (int r = 0; r < 4; ++r) {
        float va = acc1a[mt][r];
        float ia = va * (1.f + 0.044715f * va * va);
        float ea = __expf(-1.5957691216057308f * ia);
        Hs[0][(mt * 16 + quad * 4 + r) * 136 + wv * 16 + l15] =
            f2bf(va * __builtin_amdgcn_rcpf(1.f + ea));
        float vb = acc1b[mt][r];
        float ib = vb * (1.f + 0.044715f * vb * vb);
        float eb = __expf(-1.5957691216057308f * ib);
        Hs[1][(mt * 16 + quad * 4 + r) * 136 + wv * 16 + l15] =
            f2bf(vb * __builtin_amdgcn_rcpf(1.f + eb));
      }
    __syncthreads();
    #pragma unroll
    for (int buf = 0; buf < 2; ++buf) {
      int hc = 2 * hp + buf;
      #pragma unroll
      for (int ks = 0; ks < 4; ++ks) {
        short8 bf2[2];
        #pragma unroll
        for (int nt = 0; nt < 2; ++nt)
          bf2[nt] = *(const short8*)(W2f + ((((size_t)hc * 4 + ks) * 16 + wv * 2 + nt) * 64 + lane) * 8);
        __builtin_amdgcn_s_setprio(1);
        #pragma unroll
        for (int mt = 0; mt < 4; ++mt) {
          short8 af2 = *(const short8*)&Hs[buf][(mt * 16 + l15) * 136 + ks * 32 + quad * 8];
          #pragma unroll
          for (int nt = 0; nt < 2; ++nt)
            acc2[mt][nt] = __builtin_amdgcn_mfma_f32_16x16x32_bf16(af2, bf2[nt], acc2[mt][nt], 0, 0, 0);
        }
        __builtin_amdgcn_s_setprio(0);
      }
    }
    __syncthreads();
  }

  #pragma unroll
  for (int mt = 0; mt < 4; ++mt)
    #pragma unroll
    for (int nt = 0; nt < 2; ++nt)
      #pragma unroll
      for (int r = 0; r < 4; ++r) {
        size_t idx = (size_t)(m0 + mt * 16 + quad * 4 + r) * 256 + wv * 32 + nt * 16 + l15;
        out[idx] = xin[idx] + acc2[mt][nt][r];
      }
}

// ---------------- fused window attention v4 (kept from round 7) -------------
__global__ __launch_bounds__(256, 4) void attn_v3(const u16* __restrict__ qkv,
                                                  const u16* __restrict__ biasb,
                                                  int layer, u16* __restrict__ aout) {
  __shared__ u16 Klds[256 * 32];
  __shared__ u16 Vt[32 * 264];
  __shared__ u16 Plds[4][16 * 40];
  int bid = blockIdx.x;
  int lw = ((bid & 7) << 7) | (bid >> 3);   // XCD swizzle
  int w = lw >> 3, h = lw & 7;
  int tid = threadIdx.x;

  {
    const uint4* kp = (const uint4*)(qkv + ((size_t)(w * 256 + tid)) * 768 + 256 + h * 32);
    uint4* kd = (uint4*)&Klds[tid * 32];
    kd[0] = kp[0]; kd[1] = kp[1]; kd[2] = kp[2]; kd[3] = kp[3];
    const uint4* vp = (const uint4*)(qkv + ((size_t)(w * 256 + tid)) * 768 + 512 + h * 32);
    u16 vt[32];
    *(uint4*)&vt[0]  = vp[0];
    *(uint4*)&vt[8]  = vp[1];
    *(uint4*)&vt[16] = vp[2];
    *(uint4*)&vt[24] = vp[3];
    #pragma unroll
    for (int d = 0; d < 32; ++d) Vt[d * 264 + tid] = vt[d];
  }
  __syncthreads();

  int wv = tid >> 6, lane = tid & 63, quad = lane >> 4, l15 = lane & 15;
  int wi = w & 15, wr = wi >> 2, wc = wi & 3;
  const bool masked = (layer != 0) && (wr == 3 || wc == 3);
  int ckey_w = (wc == 3) ? (quad < 2 ? 1 : 2) : 0;
  int cq_w = (wc == 3) ? (l15 < 8 ? 1 : 2) : 0;

  #pragma unroll
  for (int mt = 0; mt < 4; ++mt) {
    int mslot = wv * 4 + mt;
    int m0 = mslot * 16;
    short8 aq = *(const short8*)(qkv + ((size_t)(w * 256 + m0 + l15)) * 768 + h * 32 + quad * 8);
    const u16* bmt = biasb + ((size_t)layer << 19) + ((size_t)h << 16) + (size_t)mslot * 4096;
    f32x4 c[16];
    #pragma unroll
    for (int k = 0; k < 8; ++k) {
      short8 bv = *(const short8*)(bmt + k * 512 + lane * 8);
      #pragma unroll
      for (int r = 0; r < 4; ++r) {
        c[2 * k][r]     = bf2f((u16)bv[r]);
        c[2 * k + 1][r] = bf2f((u16)bv[4 + r]);
      }
    }
    #pragma unroll
    for (int nt = 0; nt < 16; ++nt) {
      short8 bk = *(const short8*)&Klds[(nt * 16 + l15) * 32 + quad * 8];
      c[nt] = __builtin_amdgcn_mfma_f32_16x16x32_bf16(bk, aq, c[nt], 0, 0, 0);
    }
    if (masked) {
      int regi = ((wr == 3) ? (mslot < 8 ? 1 : 2) : 0) * 3 + cq_w;
      #pragma unroll
      for (int nt = 0; nt < 16; ++nt) {
        int regj = ((wr == 3) ? (nt < 8 ? 1 : 2) : 0) * 3 + ckey_w;
        float madd = (regi != regj) ? -100.f : 0.f;
        #pragma unroll
        for (int r = 0; r < 4; ++r) c[nt][r] += madd;
      }
    }
    float pm = -1e30f;
    #pragma unroll
    for (int nt = 0; nt < 16; ++nt)
      #pragma unroll
      for (int r = 0; r < 4; ++r) pm = fmaxf(pm, c[nt][r]);
    pm = fmaxf(pm, __shfl_xor(pm, 16, 64));
    pm = fmaxf(pm, __shfl_xor(pm, 32, 64));
    float ps = 0.f;
    #pragma unroll
    for (int nt = 0; nt < 16; ++nt)
      #pragma unroll
      for (int r = 0; r < 4; ++r) {
        float e = __expf(c[nt][r] - pm);
        c[nt][r] = e;
        ps += e;
      }
    ps += __shfl_xor(ps, 16, 64);
    ps += __shfl_xor(ps, 32, 64);
    float inv = 1.f / ps;

    f32x4 o0 = {0.f, 0.f, 0.f, 0.f}, o1 = {0.f, 0.f, 0.f, 0.f};
    #pragma unroll
    for (int kk = 0; kk < 8; ++kk) {
      uint2 wA, wB;
      wA.x = cvt_pk_bf16(c[2 * kk][0] * inv, c[2 * kk][1] * inv);
      wA.y = cvt_pk_bf16(c[2 * kk][2] * inv, c[2 * kk][3] * inv);
      wB.x = cvt_pk_bf16(c[2 * kk + 1][0] * inv, c[2 * kk + 1][1] * inv);
      wB.y = cvt_pk_bf16(c[2 * kk + 1][2] * inv, c[2 * kk + 1][3] * inv);
      *(uint2*)&Plds[wv][l15 * 40 + quad * 4] = wA;
      *(uint2*)&Plds[wv][l15 * 40 + 16 + quad * 4] = wB;
      short8 ap = *(const short8*)&Plds[wv][l15 * 40 + quad * 8];
      short8 bv0 = *(const short8*)&Vt[l15 * 264 + kk * 32 + quad * 8];
      short8 bv1 = *(const short8*)&Vt[(16 + l15) * 264 + kk * 32 + quad * 8];
      o0 = __builtin_amdgcn_mfma_f32_16x16x32_bf16(ap, bv0, o0, 0, 0, 0);
      o1 = __builtin_amdgcn_mfma_f32_16x16x32_bf16(ap, bv1, o1, 0, 0, 0);
    }
    #pragma unroll
    for (int r = 0; r < 4; ++r) {
      size_t row = (size_t)(w * 256 + m0 + quad * 4 + r);
      aout[row * 256 + h * 32 + l15] = f2bf(o0[r]);
      aout[row * 256 + h * 32 + 16 + l15] = f2bf(o1[r]);
    }
  }
}

// ----------------------------------------------------------------------------
extern "C" void kernel_launch(void* const* d_in, const int* in_sizes, int n_in,
                              void* d_out, int out_size, void* d_ws, size_t ws_size,
                              hipStream_t stream) {
  const float* x      = (const float*)d_in[0];
  const float* ln1_g  = (const float*)d_in[1];
  const float* ln1_b  = (const float*)d_in[2];
  const float* qkv_w  = (const float*)d_in[3];
  const float* qkv_b  = (const float*)d_in[4];
  const float* rpb    = (const float*)d_in[5];
  const float* proj_w = (const float*)d_in[6];
  const float* proj_b = (const float*)d_in[7];
  const float* ln2_g  = (const float*)d_in[8];
  const float* ln2_b  = (const float*)d_in[9];
  const float* fc1_w  = (const float*)d_in[10];
  const float* fc1_b  = (const float*)d_in[11];
  const float* fc2_w  = (const float*)d_in[12];
  const float* fc2_b  = (const float*)d_in[13];
  const int*   rpi    = (const int*)d_in[15];

  char* ws = (char*)d_ws;
  size_t off = 0;
  auto alloc = [&](size_t bytes) { void* p = ws + off; off += (bytes + 255) & ~(size_t)255; return p; };
  float* x_cur   = (float*)alloc((size_t)32768 * 256 * 4);   // residual stream
  u16* sbuf      = (u16*)alloc((size_t)32768 * 256 * 2);     // attn_out
  u16* qkvb      = (u16*)alloc((size_t)32768 * 768 * 2);
  u16* biasb     = (u16*)alloc((size_t)2 * 8 * 65536 * 2);   // pre-swizzled bf16 bias
  u16* qkvF      = (u16*)alloc((size_t)2 * 196608 * 2);      // qkv B-fragments
  u16* projF     = (u16*)alloc((size_t)2 * 65536 * 2);       // proj B-fragments
  u16* W1f       = (u16*)alloc((size_t)2 * 262144 * 2);      // fc1 B-fragments
  u16* W2f       = (u16*)alloc((size_t)2 * 262144 * 2);      // fc2 B-fragments

  // prep
  wswizB<<<192, 256, 0, stream>>>(qkv_w, qkvF, 256, 768);
  wswizB<<<64, 256, 0, stream>>>(proj_w, projF, 256, 256);
  wswiz1<<<256, 256, 0, stream>>>(fc1_w, W1f);
  wswiz2<<<256, 256, 0, stream>>>(fc2_w, W2f);
  bias_gb<<<512, 256, 0, stream>>>(rpb, rpi, biasb);

  for (int i = 0; i < 2; ++i) {
    int shift = i ? 8 : 0;
    const float* xin = i ? x_cur : x;

    EpiParams ep{};
    ep.bias = qkv_b + i * 768; ep.obf = qkvb; ep.qscale = 0.17677669529663687f;
    ep.shift = shift;
    ln_qkv<<<dim3(3, 256), 512, 0, stream>>>(xin, ln1_g + i * 256, ln1_b + i * 256,
                                             qkvF + (size_t)i * 196608, 768, ep);

    attn_v3<<<1024, 256, 0, stream>>>(qkvb, biasb, i, sbuf);

    ep = EpiParams{};
    ep.bias = proj_b + i * 256; ep.of32 = x_cur; ep.resid = xin; ep.shift = shift;
    gemm_fk<2><<<dim3(2, 256), 512, 0, stream>>>(sbuf, projF + (size_t)i * 65536, 256, ep);

    fused_mlp<<<512, 512, 0, stream>>>(x_cur, ln2_g + i * 256, ln2_b + i * 256,
                                       W1f + (size_t)i * 262144, W2f + (size_t)i * 262144,
                                       fc1_b + i * 1024, fc2_b + i * 256,
                                       (i == 1) ? (float*)d_out : x_cur);
  }
}

// Round 9
// 390.404 us; speedup vs baseline: 1.1118x; 1.0044x over previous
//
#include <hip/hip_runtime.h>

typedef unsigned short u16;
typedef __attribute__((ext_vector_type(8))) short short8;
typedef __attribute__((ext_vector_type(4))) float f32x4;

#define GLDS16(gp, sp) __builtin_amdgcn_global_load_lds( \
    (const __attribute__((address_space(1))) void*)(gp),  \
    (__attribute__((address_space(3))) void*)(sp), 16, 0, 0)

__device__ __forceinline__ u16 f2bf(float f) {
  union { float f; unsigned u; } x; x.f = f;
  unsigned r = (x.u + 0x7fffu + ((x.u >> 16) & 1u)) >> 16;  // RNE
  return (u16)r;
}
__device__ __forceinline__ float bf2f(u16 v) {
  union { unsigned u; float f; } x; x.u = ((unsigned)v) << 16; return x.f;
}
__device__ __forceinline__ unsigned cvt_pk_bf16(float lo, float hi) {
  unsigned r;
  asm("v_cvt_pk_bf16_f32 %0, %1, %2" : "=v"(r) : "v"(lo), "v"(hi));
  return r;
}

// ------- generic weight -> bf16 MFMA B-fragment order --------------------
__global__ __launch_bounds__(256) void wswizB(const float* __restrict__ W,
                                              u16* __restrict__ Wf, int K, int N) {
  int tid = blockIdx.x * 256 + threadIdx.x;
  int Kt = K >> 5, Nt = N >> 4;
  int per = Nt * Kt * 64;
  if (tid >= 2 * per) return;
  int l = tid >= per;
  int rem = tid - l * per;
  int nb = rem / (Kt * 64);
  int rem2 = rem - nb * Kt * 64;
  int ks = rem2 >> 6, lane = rem2 & 63;
  int n = nb * 16 + (lane & 15);
  u16 o[8];
  #pragma unroll
  for (int e = 0; e < 8; ++e) {
    int k = ks * 32 + ((lane >> 4) << 3) + e;
    o[e] = f2bf(W[((size_t)l * K + k) * N + n]);
  }
  *(uint4*)(Wf + ((size_t)tid << 3)) = *(uint4*)o;
}

// ------- fc1 weights -> B-fragment order: W1f[l][hc(8)][ks(8)][ntile(8)][lane][8]
__global__ __launch_bounds__(256) void wswiz1(const float* __restrict__ W,
                                              u16* __restrict__ Wf) {
  int tid = blockIdx.x * 256 + threadIdx.x;  // [0, 65536)
  int lane = tid & 63, nt = (tid >> 6) & 7, ks = (tid >> 9) & 7,
      hc = (tid >> 12) & 7, l = tid >> 15;
  int n = hc * 128 + nt * 16 + (lane & 15);
  u16 o[8];
  #pragma unroll
  for (int e = 0; e < 8; ++e) {
    int k = ks * 32 + ((lane >> 4) << 3) + e;
    o[e] = f2bf(W[((size_t)l * 256 + k) * 1024 + n]);
  }
  *(uint4*)(Wf + ((size_t)tid << 3)) = *(uint4*)o;
}

// ------- fc2 weights -> B-fragment order: W2f[l][hc(8)][ks(4)][ntile(16)][lane][8]
__global__ __launch_bounds__(256) void wswiz2(const float* __restrict__ W,
                                              u16* __restrict__ Wf) {
  int tid = blockIdx.x * 256 + threadIdx.x;  // [0, 65536)
  int lane = tid & 63, nt = (tid >> 6) & 15, ks = (tid >> 10) & 3,
      hc = (tid >> 12) & 7, l = tid >> 15;
  int n = nt * 16 + (lane & 15);
  u16 o[8];
  #pragma unroll
  for (int e = 0; e < 8; ++e) {
    int k = hc * 128 + ks * 32 + ((lane >> 4) << 3) + e;
    o[e] = f2bf(W[((size_t)l * 1024 + k) * 256 + n]);
  }
  *(uint4*)(Wf + ((size_t)tid << 3)) = *(uint4*)o;
}

// ------- rel-pos bias gather, bf16, SWAPPED layout, pre-scaled by log2(e) ---
// (exp2 folding: attn uses exp2f, so bias/mask/qscale all carry log2e.)
__global__ __launch_bounds__(256) void bias_gb(const float* __restrict__ rpb,
                                               const int* __restrict__ rpi,
                                               u16* __restrict__ biasb) {
  int tid = blockIdx.x * 256 + threadIdx.x;  // [0, 2*65536)
  if (tid >= 131072) return;
  int l = tid >> 16, cid = tid & 65535;
  int lane = cid & 63, k = (cid >> 6) & 7, mslot = (cid >> 9) & 15, h = cid >> 13;
  u16 o[8];
  #pragma unroll
  for (int e = 0; e < 8; ++e) {
    int nt = 2 * k + (e >> 2), r = e & 3;
    int i = mslot * 16 + (lane & 15);              // query
    int j = nt * 16 + ((lane >> 4) << 2) + r;      // key
    int idx = rpi[i * 256 + j];
    o[e] = f2bf(rpb[((size_t)l * 961 + idx) * 8 + h] * 1.4426950409f);
  }
  *(uint4*)(biasb + ((size_t)tid << 3)) = *(uint4*)o;
}

struct EpiParams {
  const float* bias;
  u16* obf;
  float* of32;
  const float* resid;
  int shift;
  float qscale;
};

// ---------------- fused LN1 + window partition + qkv GEMM -------------------
__global__ __launch_bounds__(512, 2) void ln_qkv(const float* __restrict__ x,
                                                 const float* __restrict__ g,
                                                 const float* __restrict__ b,
                                                 const u16* __restrict__ Wf,
                                                 int N, EpiParams ep) {
  __shared__ u16 As[8][128][32];   // 64 KB
  int tid = threadIdx.x;
  int n0 = blockIdx.x * 256, m0 = blockIdx.y * 128;
  int wv = tid >> 6, lane = tid & 63, quad = lane >> 4, l15 = lane & 15;
  int wm = wv & 1, wn = wv >> 1;   // wn in 0..3

  // ---- LN staging: 16 rows per wave, thread owns 4 channels (lane*4..+3)
  {
    float4 gg = *(const float4*)(g + lane * 4);
    float4 bb = *(const float4*)(b + lane * 4);
    #pragma unroll
    for (int rr = 0; rr < 16; ++rr) {
      int row = wv * 16 + rr;
      int wtok = m0 + row;
      int w = wtok >> 8, t = wtok & 255;
      int bimg = w >> 4, wi = w & 15;
      int ph = (((wi >> 2) << 4) + (t >> 4) + ep.shift) & 63;
      int pw = (((wi & 3) << 4) + (t & 15) + ep.shift) & 63;
      const float4 v = *(const float4*)(x + ((size_t)((bimg * 64 + ph) * 64 + pw)) * 256 + lane * 4);
      float s = v.x + v.y + v.z + v.w;
      float sq = v.x * v.x + v.y * v.y + v.z * v.z + v.w * v.w;
      #pragma unroll
      for (int m = 1; m < 64; m <<= 1) { s += __shfl_xor(s, m, 64); sq += __shfl_xor(sq, m, 64); }
      float mean = s * (1.f / 256.f);
      float rs = rsqrtf(sq * (1.f / 256.f) - mean * mean + 1e-5f);
      uint2 pk;
      pk.x = cvt_pk_bf16((v.x - mean) * rs * gg.x + bb.x,
                         (v.y - mean) * rs * gg.y + bb.y);
      pk.y = cvt_pk_bf16((v.z - mean) * rs * gg.z + bb.z,
                         (v.w - mean) * rs * gg.w + bb.w);
      *(uint2*)&As[lane >> 3][row][(lane & 7) * 4] = pk;
    }
  }
  __syncthreads();

  f32x4 acc[4][4] = {};
  #pragma unroll
  for (int kb = 0; kb < 8; ++kb) {
    short8 bf[4];
    #pragma unroll
    for (int nt = 0; nt < 4; ++nt) {
      size_t ntile = (size_t)(blockIdx.x * 16 + wn * 4 + nt);
      bf[nt] = *(const short8*)(Wf + ((ntile * 8 + kb) * 64 + lane) * 8);
    }
    #pragma unroll
    for (int mt = 0; mt < 4; ++mt) {
      short8 af = *(const short8*)&As[kb][wm * 64 + mt * 16 + l15][quad * 8];
      #pragma unroll
      for (int nt = 0; nt < 4; ++nt)
        acc[mt][nt] = __builtin_amdgcn_mfma_f32_16x16x32_bf16(af, bf[nt], acc[mt][nt], 0, 0, 0);
    }
  }

  #pragma unroll
  for (int mt = 0; mt < 4; ++mt) {
    #pragma unroll
    for (int nt = 0; nt < 4; ++nt) {
      #pragma unroll
      for (int r = 0; r < 4; ++r) {
        int grow = m0 + wm * 64 + mt * 16 + quad * 4 + r;
        int gcol = n0 + wn * 64 + nt * 16 + l15;
        float v = acc[mt][nt][r] + ep.bias[gcol];
        if (gcol < 256) v *= ep.qscale;
        ep.obf[(size_t)grow * N + gcol] = f2bf(v);
      }
    }
  }
}

// ---------------- proj GEMM: swapped operands -> float4 epilogue ------------
// mfma(bf, af) transposes C: lane holds 4 CONSECUTIVE channels (quad*4+r) of
// one token (l15). The EPI=2 scatter epilogue (32 scalar loads + 32 scalar
// stores + per-element pix math) becomes 8 float4 loads + 8 float4 stores +
// one pix computation per mt. Fragment loads identical to gemm_fk.
__global__ __launch_bounds__(512, 2) void proj_fk(const u16* __restrict__ A,
                                                  const u16* __restrict__ Wf,
                                                  EpiParams ep) {
  __shared__ u16 As[8][128][32];   // 64 KB
  int tid = threadIdx.x;
  int n0 = blockIdx.x * 128, m0 = blockIdx.y * 128;
  int wv = tid >> 6, lane = tid & 63, quad = lane >> 4, l15 = lane & 15;
  int wm = wv & 1, wn = wv >> 1;

  #pragma unroll
  for (int i = 0; i < 8; ++i) {
    int c = i * 512 + tid;
    int kb = c >> 9, rc = c & 511;
    int row = rc >> 2, kc = (rc & 3) * 8;
    GLDS16(A + (size_t)(m0 + row) * 256 + kb * 32 + kc, &As[kb][row][kc]);
  }
  __syncthreads();

  f32x4 acc[4][2] = {};
  #pragma unroll
  for (int kb = 0; kb < 8; ++kb) {
    short8 bf[2];
    #pragma unroll
    for (int nt = 0; nt < 2; ++nt) {
      size_t ntile = (size_t)(blockIdx.x * 8 + wn * 2 + nt);
      bf[nt] = *(const short8*)(Wf + ((ntile * 8 + kb) * 64 + lane) * 8);
    }
    #pragma unroll
    for (int mt = 0; mt < 4; ++mt) {
      short8 af = *(const short8*)&As[kb][wm * 64 + mt * 16 + l15][quad * 8];
      #pragma unroll
      for (int nt = 0; nt < 2; ++nt)
        acc[mt][nt] = __builtin_amdgcn_mfma_f32_16x16x32_bf16(bf[nt], af, acc[mt][nt], 0, 0, 0);
    }
  }

  // epilogue: C rows = channels (quad*4+r), cols = tokens (l15)
  #pragma unroll
  for (int mt = 0; mt < 4; ++mt) {
    int token = m0 + wm * 64 + mt * 16 + l15;
    int w_ = token >> 8, t = token & 255, wi = w_ & 15;
    int ph = (((wi >> 2) << 4) + (t >> 4) + ep.shift) & 63;
    int pw = (((wi & 3) << 4) + (t & 15) + ep.shift) & 63;
    size_t pix = (size_t)(((w_ >> 4) * 64 + ph) * 64 + pw);
    const float* rp = ep.resid + pix * 256;
    float* op = ep.of32 + pix * 256;
    #pragma unroll
    for (int nt = 0; nt < 2; ++nt) {
      int chan = n0 + wn * 32 + nt * 16 + quad * 4;
      float4 rd = *(const float4*)(rp + chan);
      float4 b4 = *(const float4*)(ep.bias + chan);
      float4 o;
      o.x = rd.x + acc[mt][nt][0] + b4.x;
      o.y = rd.y + acc[mt][nt][1] + b4.y;
      o.z = rd.z + acc[mt][nt][2] + b4.z;
      o.w = rd.w + acc[mt][nt][3] + b4.w;
      *(float4*)(op + chan) = o;
    }
  }
}

// ---------------- fused MLP v9 (parked: best measured structure) ------------
__global__ __launch_bounds__(512, 4) void fused_mlp(const float* __restrict__ xin,
                                                    const float* __restrict__ g,
                                                    const float* __restrict__ b,
                                                    const u16* __restrict__ W1f,
                                                    const u16* __restrict__ W2f,
                                                    const float* __restrict__ b1p,
                                                    const float* __restrict__ b2p,
                                                    float* __restrict__ out) {
  __shared__ u16 Zs[64 * 264];
  __shared__ u16 Hs[2][64 * 136];
  int tid = threadIdx.x, wv = tid >> 6, lane = tid & 63;
  int quad = lane >> 4, l15 = lane & 15;
  int m0 = blockIdx.x * 64;

  float4 gg = *(const float4*)(g + lane * 4);
  float4 bb = *(const float4*)(b + lane * 4);
  #pragma unroll
  for (int rr = 0; rr < 8; ++rr) {
    int row = wv * 8 + rr;
    const float4 v = *(const float4*)(xin + (size_t)(m0 + row) * 256 + lane * 4);
    float s = v.x + v.y + v.z + v.w;
    float sq = v.x * v.x + v.y * v.y + v.z * v.z + v.w * v.w;
    #pragma unroll
    for (int m = 1; m < 64; m <<= 1) { s += __shfl_xor(s, m, 64); sq += __shfl_xor(sq, m, 64); }
    float mean = s * (1.f / 256.f);
    float var = sq * (1.f / 256.f) - mean * mean;
    float rs = rsqrtf(var + 1e-5f);
    u16 o0 = f2bf((v.x - mean) * rs * gg.x + bb.x);
    u16 o1 = f2bf((v.y - mean) * rs * gg.y + bb.y);
    u16 o2 = f2bf((v.z - mean) * rs * gg.z + bb.z);
    u16 o3 = f2bf((v.w - mean) * rs * gg.w + bb.w);
    uint2 pk; pk.x = (unsigned)o0 | ((unsigned)o1 << 16); pk.y = (unsigned)o2 | ((unsigned)o3 << 16);
    *(uint2*)&Zs[row * 264 + lane * 4] = pk;
  }
  __syncthreads();

  f32x4 acc2[4][2];
  #pragma unroll
  for (int nt = 0; nt < 2; ++nt) {
    float b2 = b2p[wv * 32 + nt * 16 + l15];
    #pragma unroll
    for (int mt = 0; mt < 4; ++mt)
      #pragma unroll
      for (int r = 0; r < 4; ++r) acc2[mt][nt][r] = b2;
  }

  for (int hp = 0; hp < 4; ++hp) {
    int hcA = 2 * hp, hcB = 2 * hp + 1;
    f32x4 acc1a[4], acc1b[4];
    {
      float b1a = b1p[hcA * 128 + wv * 16 + l15];
      float b1b = b1p[hcB * 128 + wv * 16 + l15];
      #pragma unroll
      for (int mt = 0; mt < 4; ++mt)
        #pragma unroll
        for (int r = 0; r < 4; ++r) { acc1a[mt][r] = b1a; acc1b[mt][r] = b1b; }
    }
    #pragma unroll
    for (int ks = 0; ks < 8; ++ks) {
      short8 bfa = *(const short8*)(W1f + ((((size_t)hcA * 8 + ks) * 8 + wv) * 64 + lane) * 8);
      short8 bfb = *(const short8*)(W1f + ((((size_t)hcB * 8 + ks) * 8 + wv) * 64 + lane) * 8);
      __builtin_amdgcn_s_setprio(1);
      #pragma unroll
      for (int mt = 0; mt < 4; ++mt) {
        short8 af = *(const short8*)&Zs[(mt * 16 + l15) * 264 + ks * 32 + quad * 8];
        acc1a[mt] = __builtin_amdgcn_mfma_f32_16x16x32_bf16(af, bfa, acc1a[mt], 0, 0, 0);
        acc1b[mt] = __builtin_amdgcn_mfma_f32_16x16x32_bf16(af, bfb, acc1b[mt], 0, 0, 0);
      }
      __builtin_amdgcn_s_setprio(0);
    }
    #pragma unroll
    for (int mt = 0; mt < 4; ++mt)
      #pragma unroll
      for (int r = 0; r < 4; ++r) {
        float va = acc1a[mt][r];
        float ia = va * (1.f + 0.044715f * va * va);
        float ea = __expf(-1.5957691216057308f * ia);
        Hs[0][(mt * 16 + quad * 4 + r) * 136 + wv * 16 + l15] =
            f2bf(va * __builtin_amdgcn_rcpf(1.f + ea));
        float vb = acc1b[mt][r];
        float ib = vb * (1.f + 0.044715f * vb * vb);
        float eb = __expf(-1.5957691216057308f * ib);
        Hs[1][(mt * 16 + quad * 4 + r) * 136 + wv * 16 + l15] =
            f2bf(vb * __builtin_amdgcn_rcpf(1.f + eb));
      }
    __syncthreads();
    #pragma unroll
    for (int buf = 0; buf < 2; ++buf) {
      int hc = 2 * hp + buf;
      #pragma unroll
      for (int ks = 0; ks < 4; ++ks) {
        short8 bf2[2];
        #pragma unroll
        for (int nt = 0; nt < 2; ++nt)
          bf2[nt] = *(const short8*)(W2f + ((((size_t)hc * 4 + ks) * 16 + wv * 2 + nt) * 64 + lane) * 8);
        __builtin_amdgcn_s_setprio(1);
        #pragma unroll
        for (int mt = 0; mt < 4; ++mt) {
          short8 af2 = *(const short8*)&Hs[buf][(mt * 16 + l15) * 136 + ks * 32 + quad * 8];
          #pragma unroll
          for (int nt = 0; nt < 2; ++nt)
            acc2[mt][nt] = __builtin_amdgcn_mfma_f32_16x16x32_bf16(af2, bf2[nt], acc2[mt][nt], 0, 0, 0);
        }
        __builtin_amdgcn_s_setprio(0);
      }
    }
    __syncthreads();
  }

  #pragma unroll
  for (int mt = 0; mt < 4; ++mt)
    #pragma unroll
    for (int nt = 0; nt < 2; ++nt)
      #pragma unroll
      for (int r = 0; r < 4; ++r) {
        size_t idx = (size_t)(m0 + mt * 16 + quad * 4 + r) * 256 + wv * 32 + nt * 16 + l15;
        out[idx] = xin[idx] + acc2[mt][nt][r];
      }
}

// ---------------- fused window attention v4 + exp2 folding ------------------
// qscale/bias/mask carry log2(e); softmax uses exp2f (saves 256 v_mul/thread).
__global__ __launch_bounds__(256, 4) void attn_v3(const u16* __restrict__ qkv,
                                                  const u16* __restrict__ biasb,
                                                  int layer, u16* __restrict__ aout) {
  __shared__ u16 Klds[256 * 32];
  __shared__ u16 Vt[32 * 264];
  __shared__ u16 Plds[4][16 * 40];
  int bid = blockIdx.x;
  int lw = ((bid & 7) << 7) | (bid >> 3);   // XCD swizzle
  int w = lw >> 3, h = lw & 7;
  int tid = threadIdx.x;

  {
    const uint4* kp = (const uint4*)(qkv + ((size_t)(w * 256 + tid)) * 768 + 256 + h * 32);
    uint4* kd = (uint4*)&Klds[tid * 32];
    kd[0] = kp[0]; kd[1] = kp[1]; kd[2] = kp[2]; kd[3] = kp[3];
    const uint4* vp = (const uint4*)(qkv + ((size_t)(w * 256 + tid)) * 768 + 512 + h * 32);
    u16 vt[32];
    *(uint4*)&vt[0]  = vp[0];
    *(uint4*)&vt[8]  = vp[1];
    *(uint4*)&vt[16] = vp[2];
    *(uint4*)&vt[24] = vp[3];
    #pragma unroll
    for (int d = 0; d < 32; ++d) Vt[d * 264 + tid] = vt[d];
  }
  __syncthreads();

  int wv = tid >> 6, lane = tid & 63, quad = lane >> 4, l15 = lane & 15;
  int wi = w & 15, wr = wi >> 2, wc = wi & 3;
  const bool masked = (layer != 0) && (wr == 3 || wc == 3);
  int ckey_w = (wc == 3) ? (quad < 2 ? 1 : 2) : 0;
  int cq_w = (wc == 3) ? (l15 < 8 ? 1 : 2) : 0;

  #pragma unroll
  for (int mt = 0; mt < 4; ++mt) {
    int mslot = wv * 4 + mt;
    int m0 = mslot * 16;
    short8 aq = *(const short8*)(qkv + ((size_t)(w * 256 + m0 + l15)) * 768 + h * 32 + quad * 8);
    const u16* bmt = biasb + ((size_t)layer << 19) + ((size_t)h << 16) + (size_t)mslot * 4096;
    f32x4 c[16];
    #pragma unroll
    for (int k = 0; k < 8; ++k) {
      short8 bv = *(const short8*)(bmt + k * 512 + lane * 8);
      #pragma unroll
      for (int r = 0; r < 4; ++r) {
        c[2 * k][r]     = bf2f((u16)bv[r]);
        c[2 * k + 1][r] = bf2f((u16)bv[4 + r]);
      }
    }
    #pragma unroll
    for (int nt = 0; nt < 16; ++nt) {
      short8 bk = *(const short8*)&Klds[(nt * 16 + l15) * 32 + quad * 8];
      c[nt] = __builtin_amdgcn_mfma_f32_16x16x32_bf16(bk, aq, c[nt], 0, 0, 0);
    }
    if (masked) {
      int regi = ((wr == 3) ? (mslot < 8 ? 1 : 2) : 0) * 3 + cq_w;
      #pragma unroll
      for (int nt = 0; nt < 16; ++nt) {
        int regj = ((wr == 3) ? (nt < 8 ? 1 : 2) : 0) * 3 + ckey_w;
        float madd = (regi != regj) ? -144.2695041f : 0.f;   // -100 * log2(e)
        #pragma unroll
        for (int r = 0; r < 4; ++r) c[nt][r] += madd;
      }
    }
    float pm = -1e30f;
    #pragma unroll
    for (int nt = 0; nt < 16; ++nt)
      #pragma unroll
      for (int r = 0; r < 4; ++r) pm = fmaxf(pm, c[nt][r]);
    pm = fmaxf(pm, __shfl_xor(pm, 16, 64));
    pm = fmaxf(pm, __shfl_xor(pm, 32, 64));
    float ps = 0.f;
    #pragma unroll
    for (int nt = 0; nt < 16; ++nt)
      #pragma unroll
      for (int r = 0; r < 4; ++r) {
        float e = exp2f(c[nt][r] - pm);
        c[nt][r] = e;
        ps += e;
      }
    ps += __shfl_xor(ps, 16, 64);
    ps += __shfl_xor(ps, 32, 64);
    float inv = 1.f / ps;

    f32x4 o0 = {0.f, 0.f, 0.f, 0.f}, o1 = {0.f, 0.f, 0.f, 0.f};
    #pragma unroll
    for (int kk = 0; kk < 8; ++kk) {
      uint2 wA, wB;
      wA.x = cvt_pk_bf16(c[2 * kk][0] * inv, c[2 * kk][1] * inv);
      wA.y = cvt_pk_bf16(c[2 * kk][2] * inv, c[2 * kk][3] * inv);
      wB.x = cvt_pk_bf16(c[2 * kk + 1][0] * inv, c[2 * kk + 1][1] * inv);
      wB.y = cvt_pk_bf16(c[2 * kk + 1][2] * inv, c[2 * kk + 1][3] * inv);
      *(uint2*)&Plds[wv][l15 * 40 + quad * 4] = wA;
      *(uint2*)&Plds[wv][l15 * 40 + 16 + quad * 4] = wB;
      short8 ap = *(const short8*)&Plds[wv][l15 * 40 + quad * 8];
      short8 bv0 = *(const short8*)&Vt[l15 * 264 + kk * 32 + quad * 8];
      short8 bv1 = *(const short8*)&Vt[(16 + l15) * 264 + kk * 32 + quad * 8];
      o0 = __builtin_amdgcn_mfma_f32_16x16x32_bf16(ap, bv0, o0, 0, 0, 0);
      o1 = __builtin_amdgcn_mfma_f32_16x16x32_bf16(ap, bv1, o1, 0, 0, 0);
    }
    #pragma unroll
    for (int r = 0; r < 4; ++r) {
      size_t row = (size_t)(w * 256 + m0 + quad * 4 + r);
      aout[row * 256 + h * 32 + l15] = f2bf(o0[r]);
      aout[row * 256 + h * 32 + 16 + l15] = f2bf(o1[r]);
    }
  }
}

// ----------------------------------------------------------------------------
extern "C" void kernel_launch(void* const* d_in, const int* in_sizes, int n_in,
                              void* d_out, int out_size, void* d_ws, size_t ws_size,
                              hipStream_t stream) {
  const float* x      = (const float*)d_in[0];
  const float* ln1_g  = (const float*)d_in[1];
  const float* ln1_b  = (const float*)d_in[2];
  const float* qkv_w  = (const float*)d_in[3];
  const float* qkv_b  = (const float*)d_in[4];
  const float* rpb    = (const float*)d_in[5];
  const float* proj_w = (const float*)d_in[6];
  const float* proj_b = (const float*)d_in[7];
  const float* ln2_g  = (const float*)d_in[8];
  const float* ln2_b  = (const float*)d_in[9];
  const float* fc1_w  = (const float*)d_in[10];
  const float* fc1_b  = (const float*)d_in[11];
  const float* fc2_w  = (const float*)d_in[12];
  const float* fc2_b  = (const float*)d_in[13];
  const int*   rpi    = (const int*)d_in[15];

  char* ws = (char*)d_ws;
  size_t off = 0;
  auto alloc = [&](size_t bytes) { void* p = ws + off; off += (bytes + 255) & ~(size_t)255; return p; };
  float* x_cur   = (float*)alloc((size_t)32768 * 256 * 4);   // residual stream
  u16* sbuf      = (u16*)alloc((size_t)32768 * 256 * 2);     // attn_out
  u16* qkvb      = (u16*)alloc((size_t)32768 * 768 * 2);
  u16* biasb     = (u16*)alloc((size_t)2 * 8 * 65536 * 2);   // pre-swizzled bf16 bias
  u16* qkvF      = (u16*)alloc((size_t)2 * 196608 * 2);      // qkv B-fragments
  u16* projF     = (u16*)alloc((size_t)2 * 65536 * 2);       // proj B-fragments
  u16* W1f       = (u16*)alloc((size_t)2 * 262144 * 2);      // fc1 B-fragments
  u16* W2f       = (u16*)alloc((size_t)2 * 262144 * 2);      // fc2 B-fragments

  // prep
  wswizB<<<192, 256, 0, stream>>>(qkv_w, qkvF, 256, 768);
  wswizB<<<64, 256, 0, stream>>>(proj_w, projF, 256, 256);
  wswiz1<<<256, 256, 0, stream>>>(fc1_w, W1f);
  wswiz2<<<256, 256, 0, stream>>>(fc2_w, W2f);
  bias_gb<<<512, 256, 0, stream>>>(rpb, rpi, biasb);

  for (int i = 0; i < 2; ++i) {
    int shift = i ? 8 : 0;
    const float* xin = i ? x_cur : x;

    EpiParams ep{};
    ep.bias = qkv_b + i * 768; ep.obf = qkvb;
    ep.qscale = 0.2550348742f;   // (1/sqrt(32)) * log2(e), exp2 folding
    ep.shift = shift;
    ln_qkv<<<dim3(3, 256), 512, 0, stream>>>(xin, ln1_g + i * 256, ln1_b + i * 256,
                                             qkvF + (size_t)i * 196608, 768, ep);

    attn_v3<<<1024, 256, 0, stream>>>(qkvb, biasb, i, sbuf);

    ep = EpiParams{};
    ep.bias = proj_b + i * 256; ep.of32 = x_cur; ep.resid = xin; ep.shift = shift;
    proj_fk<<<dim3(2, 256), 512, 0, stream>>>(sbuf, projF + (size_t)i * 65536, ep);

    fused_mlp<<<512, 512, 0, stream>>>(x_cur, ln2_g + i * 256, ln2_b + i * 256,
                                       W1f + (size_t)i * 262144, W2f + (size_t)i * 262144,
                                       fc1_b + i * 1024, fc2_b + i * 256,
                                       (i == 1) ? (float*)d_out : x_cur);
  }
}